// Round 1
// baseline (27121.164 us; speedup 1.0000x reference)
//
#include <hip/hip_runtime.h>
#include <hip/hip_bf16.h>
#include <math.h>

#define BB 4
#define TT 1024
#define DD 1024
#define HH 16
#define HSS 64
#define LL 8
#define VV 8192
#define FFD 4096
#define MM (BB*TT)   // 4096 rows

// ---------------- embedding: h = tok[x] + pos[x]  (pos indexed by TOKEN id - reference quirk)
__global__ __launch_bounds__(256) void embed_kernel(const int* __restrict__ x,
    const float* __restrict__ tok, const float* __restrict__ pos, float* __restrict__ h)
{
  int i = blockIdx.x * 256 + threadIdx.x;          // over MM*DD/4
  int row = i >> 8;                                 // DD/4 = 256 float4 per row
  int c4 = i & 255;
  int id = x[row];
  float4 a = ((const float4*)(tok + (size_t)id * DD))[c4];
  float4 b = ((const float4*)(pos + (size_t)id * DD))[c4];
  ((float4*)(h + (size_t)row * DD))[c4] = make_float4(a.x + b.x, a.y + b.y, a.z + b.z, a.w + b.w);
}

// ---------------- repack wq/wk/wv layer slice (H,D,HS) -> row-major (D, H*HS)
__global__ __launch_bounds__(256) void repack_kernel(const float* __restrict__ src, float* __restrict__ dst)
{
  int i = blockIdx.x * 256 + threadIdx.x;  // DD*HH*HSS = 1M
  int d = i >> 10;
  int c = i & 1023;
  int hh = c >> 6;
  int e = c & 63;
  dst[i] = src[(size_t)hh * DD * HSS + (size_t)d * HSS + e];
}

// ---------------- layernorm, one block per row of 1024
__global__ __launch_bounds__(256) void ln_kernel(const float* __restrict__ in,
    const float* __restrict__ g, const float* __restrict__ bta, float* __restrict__ out)
{
  __shared__ float sred[8];
  int row = blockIdx.x;
  int tid = threadIdx.x;
  float4 xv = ((const float4*)(in + (size_t)row * DD))[tid];
  float s = xv.x + xv.y + xv.z + xv.w;
  #pragma unroll
  for (int o = 32; o; o >>= 1) s += __shfl_down(s, o);
  if ((tid & 63) == 0) sred[tid >> 6] = s;
  __syncthreads();
  float mean = (sred[0] + sred[1] + sred[2] + sred[3]) * (1.f / DD);
  float d0 = xv.x - mean, d1 = xv.y - mean, d2 = xv.z - mean, d3 = xv.w - mean;
  float sq = d0 * d0 + d1 * d1 + d2 * d2 + d3 * d3;
  #pragma unroll
  for (int o = 32; o; o >>= 1) sq += __shfl_down(sq, o);
  if ((tid & 63) == 0) sred[4 + (tid >> 6)] = sq;
  __syncthreads();
  float var = (sred[4] + sred[5] + sred[6] + sred[7]) * (1.f / DD);
  float inv = rsqrtf(var + 1e-5f);
  float4 gv = ((const float4*)g)[tid];
  float4 bv = ((const float4*)bta)[tid];
  float4 ov = make_float4(d0 * inv * gv.x + bv.x, d1 * inv * gv.y + bv.y,
                          d2 * inv * gv.z + bv.z, d3 * inv * gv.w + bv.w);
  ((float4*)(out + (size_t)row * DD))[tid] = ov;
}

// ---------------- generic f32 GEMM: C[M,N] = A[M,K] @ B[K,N] (+bias)(relu)(+res)
// 64x64 block tile, BK=16, 256 threads, 4x4 per thread.
template<bool RELU, bool BIAS, bool RES>
__global__ __launch_bounds__(256) void gemm_kernel(
    const float* __restrict__ A, const float* __restrict__ Bm,
    const float* __restrict__ bias, const float* __restrict__ res,
    float* __restrict__ C, int M, int N, int K)
{
  __shared__ float As[16][64];   // As[k][m]
  __shared__ float Bs[16][64];   // Bs[k][n]
  const int bm = blockIdx.y * 64, bn = blockIdx.x * 64;
  const int tid = threadIdx.x;
  const int tm = (tid >> 4) << 2;   // 0..60
  const int tn = (tid & 15) << 2;   // 0..60
  const int ar = tid >> 2, ac = (tid & 3) << 2;
  const int br = tid >> 4, bc = (tid & 15) << 2;
  float acc[4][4] = {};
  for (int k0 = 0; k0 < K; k0 += 16) {
    float4 av = *(const float4*)(A + (size_t)(bm + ar) * K + k0 + ac);
    As[ac + 0][ar] = av.x; As[ac + 1][ar] = av.y; As[ac + 2][ar] = av.z; As[ac + 3][ar] = av.w;
    *(float4*)&Bs[br][bc] = *(const float4*)(Bm + (size_t)(k0 + br) * N + bn + bc);
    __syncthreads();
    #pragma unroll
    for (int kk = 0; kk < 16; ++kk) {
      float4 a4 = *(const float4*)&As[kk][tm];
      float4 b4 = *(const float4*)&Bs[kk][tn];
      acc[0][0] += a4.x * b4.x; acc[0][1] += a4.x * b4.y; acc[0][2] += a4.x * b4.z; acc[0][3] += a4.x * b4.w;
      acc[1][0] += a4.y * b4.x; acc[1][1] += a4.y * b4.y; acc[1][2] += a4.y * b4.z; acc[1][3] += a4.y * b4.w;
      acc[2][0] += a4.z * b4.x; acc[2][1] += a4.z * b4.y; acc[2][2] += a4.z * b4.z; acc[2][3] += a4.z * b4.w;
      acc[3][0] += a4.w * b4.x; acc[3][1] += a4.w * b4.y; acc[3][2] += a4.w * b4.z; acc[3][3] += a4.w * b4.w;
    }
    __syncthreads();
  }
  float4 bias4 = make_float4(0.f, 0.f, 0.f, 0.f);
  if (BIAS) bias4 = *(const float4*)(bias + bn + tn);
  #pragma unroll
  for (int i = 0; i < 4; ++i) {
    int row = bm + tm + i;
    float4 v = make_float4(acc[i][0], acc[i][1], acc[i][2], acc[i][3]);
    if (BIAS) { v.x += bias4.x; v.y += bias4.y; v.z += bias4.z; v.w += bias4.w; }
    if (RELU) { v.x = fmaxf(v.x, 0.f); v.y = fmaxf(v.y, 0.f); v.z = fmaxf(v.z, 0.f); v.w = fmaxf(v.w, 0.f); }
    if (RES) {
      float4 r4 = *(const float4*)(res + (size_t)row * N + bn + tn);
      v.x += r4.x; v.y += r4.y; v.z += r4.z; v.w += r4.w;
    }
    *(float4*)(C + (size_t)row * N + bn + tn) = v;
  }
}

// ---------------- causal attention, one thread per (b,h,t) row, online softmax.
// q/k/v/o layout: [b*T + t][h*64 + e]  (stride DD)
__global__ __launch_bounds__(256, 1) void attn_kernel(const float* __restrict__ q,
    const float* __restrict__ k, const float* __restrict__ v, float* __restrict__ o)
{
  int r = blockIdx.x * 256 + threadIdx.x;   // 0..B*H*T
  int t = r & (TT - 1);
  int bh = r >> 10;
  int b = bh >> 4;
  int hh = bh & 15;
  size_t base = (size_t)b * TT * DD + (size_t)hh * HSS;
  const float4* q4 = (const float4*)(q + base + (size_t)t * DD);
  float qr[64];
  #pragma unroll
  for (int e4 = 0; e4 < 16; ++e4) {
    float4 xq = q4[e4];
    qr[4*e4] = xq.x * 0.125f; qr[4*e4+1] = xq.y * 0.125f; qr[4*e4+2] = xq.z * 0.125f; qr[4*e4+3] = xq.w * 0.125f;
  }
  float m = -3.0e38f, s = 0.f;
  float acc[64];
  #pragma unroll
  for (int e = 0; e < 64; ++e) acc[e] = 0.f;
  for (int j = 0; j <= t; ++j) {
    const float4* k4 = (const float4*)(k + base + (size_t)j * DD);
    float sc = 0.f;
    #pragma unroll
    for (int e4 = 0; e4 < 16; ++e4) {
      float4 kv = k4[e4];
      sc += qr[4*e4] * kv.x + qr[4*e4+1] * kv.y + qr[4*e4+2] * kv.z + qr[4*e4+3] * kv.w;
    }
    float mn = fmaxf(m, sc);
    float f = __expf(m - mn);
    float p = __expf(sc - mn);
    s = s * f + p;
    const float4* v4 = (const float4*)(v + base + (size_t)j * DD);
    #pragma unroll
    for (int e4 = 0; e4 < 16; ++e4) {
      float4 vv = v4[e4];
      acc[4*e4]   = acc[4*e4]   * f + p * vv.x;
      acc[4*e4+1] = acc[4*e4+1] * f + p * vv.y;
      acc[4*e4+2] = acc[4*e4+2] * f + p * vv.z;
      acc[4*e4+3] = acc[4*e4+3] * f + p * vv.w;
    }
    m = mn;
  }
  float inv = 1.f / s;
  float4* o4 = (float4*)(o + base + (size_t)t * DD);
  #pragma unroll
  for (int e4 = 0; e4 < 16; ++e4)
    o4[e4] = make_float4(acc[4*e4] * inv, acc[4*e4+1] * inv, acc[4*e4+2] * inv, acc[4*e4+3] * inv);
}

extern "C" void kernel_launch(void* const* d_in, const int* in_sizes, int n_in,
                              void* d_out, int out_size, void* d_ws, size_t ws_size,
                              hipStream_t stream)
{
  const int*   x     = (const int*)d_in[0];
  const float* tok   = (const float*)d_in[1];
  const float* pos   = (const float*)d_in[2];
  const float* wq    = (const float*)d_in[3];
  const float* wk    = (const float*)d_in[4];
  const float* wv    = (const float*)d_in[5];
  const float* w_o   = (const float*)d_in[6];
  const float* b_o   = (const float*)d_in[7];
  const float* ln1_g = (const float*)d_in[8];
  const float* ln1_b = (const float*)d_in[9];
  const float* ln2_g = (const float*)d_in[10];
  const float* ln2_b = (const float*)d_in[11];
  const float* w1    = (const float*)d_in[12];
  const float* b1    = (const float*)d_in[13];
  const float* w2    = (const float*)d_in[14];
  const float* b2    = (const float*)d_in[15];
  const float* lnf_g = (const float*)d_in[16];
  const float* lnf_b = (const float*)d_in[17];
  const float* w_lm  = (const float*)d_in[18];
  const float* b_lm  = (const float*)d_in[19];
  float* out = (float*)d_out;
  float* ws  = (float*)d_ws;

  const size_t MD = (size_t)MM * DD;          // 4M floats
  float* h   = ws;                            // 4M
  float* hn  = ws + MD;                       // 4M
  float* q   = ws + 2 * MD;                   // 4M
  float* kb  = ws + 3 * MD;                   // 4M
  float* vb  = ws + 4 * MD;                   // 4M
  float* ob  = ws + 5 * MD;                   // 4M
  float* mlp = ws + 2 * MD;                   // 16M, overlays q/kb/vb/ob (dead by then)
  float* wp0 = ws + 6 * MD;                   // 1M each
  float* wp1 = wp0 + (size_t)DD * HH * HSS;
  float* wp2 = wp1 + (size_t)DD * HH * HSS;

  embed_kernel<<<dim3(MM * DD / 4 / 256), 256, 0, stream>>>(x, tok, pos, h);

  for (int l = 0; l < LL; ++l) {
    ln_kernel<<<MM, 256, 0, stream>>>(h, ln1_g + (size_t)l * DD, ln1_b + (size_t)l * DD, hn);
    size_t woff = (size_t)l * HH * DD * HSS;
    repack_kernel<<<4096, 256, 0, stream>>>(wq + woff, wp0);
    repack_kernel<<<4096, 256, 0, stream>>>(wk + woff, wp1);
    repack_kernel<<<4096, 256, 0, stream>>>(wv + woff, wp2);
    gemm_kernel<false,false,false><<<dim3(16, 64), 256, 0, stream>>>(hn, wp0, nullptr, nullptr, q,  MM, DD, DD);
    gemm_kernel<false,false,false><<<dim3(16, 64), 256, 0, stream>>>(hn, wp1, nullptr, nullptr, kb, MM, DD, DD);
    gemm_kernel<false,false,false><<<dim3(16, 64), 256, 0, stream>>>(hn, wp2, nullptr, nullptr, vb, MM, DD, DD);
    attn_kernel<<<dim3(BB * HH * TT / 256), 256, 0, stream>>>(q, kb, vb, ob);
    gemm_kernel<false,true,true><<<dim3(16, 64), 256, 0, stream>>>(ob, w_o + (size_t)l * HH * HSS * DD,
                                                                   b_o + (size_t)l * DD, hn, h, MM, DD, DD);
    ln_kernel<<<MM, 256, 0, stream>>>(h, ln2_g + (size_t)l * DD, ln2_b + (size_t)l * DD, hn);
    gemm_kernel<true,true,false><<<dim3(64, 64), 256, 0, stream>>>(hn, w1 + (size_t)l * DD * FFD,
                                                                   b1 + (size_t)l * FFD, nullptr, mlp, MM, FFD, DD);
    gemm_kernel<false,true,true><<<dim3(16, 64), 256, 0, stream>>>(mlp, w2 + (size_t)l * FFD * DD,
                                                                   b2 + (size_t)l * DD, hn, h, MM, DD, FFD);
  }
  ln_kernel<<<MM, 256, 0, stream>>>(h, lnf_g, lnf_b, hn);
  gemm_kernel<false,true,false><<<dim3(VV / 64, MM / 64), 256, 0, stream>>>(hn, w_lm, b_lm, nullptr, out, MM, VV, DD);
}

// Round 2
// 17838.336 us; speedup vs baseline: 1.5204x; 1.5204x over previous
//
#include <hip/hip_runtime.h>
#include <hip/hip_bf16.h>
#include <math.h>

#define BB 4
#define TT 1024
#define DD 1024
#define HH 16
#define HSS 64
#define LL 8
#define VV 8192
#define FFD 4096
#define MM (BB*TT)   // 4096 rows

// ---------------- embedding: h = tok[x] + pos[x]  (pos indexed by TOKEN id - reference quirk)
__global__ __launch_bounds__(256) void embed_kernel(const int* __restrict__ x,
    const float* __restrict__ tok, const float* __restrict__ pos, float* __restrict__ h)
{
  int i = blockIdx.x * 256 + threadIdx.x;          // over MM*DD/4
  int row = i >> 8;                                 // DD/4 = 256 float4 per row
  int c4 = i & 255;
  int id = x[row];
  float4 a = ((const float4*)(tok + (size_t)id * DD))[c4];
  float4 b = ((const float4*)(pos + (size_t)id * DD))[c4];
  ((float4*)(h + (size_t)row * DD))[c4] = make_float4(a.x + b.x, a.y + b.y, a.z + b.z, a.w + b.w);
}

// ---------------- repack wq/wk/wv layer slice (H,D,HS) -> row-major (D, H*HS)
__global__ __launch_bounds__(256) void repack_kernel(const float* __restrict__ src, float* __restrict__ dst)
{
  int i = blockIdx.x * 256 + threadIdx.x;  // DD*HH*HSS = 1M
  int d = i >> 10;
  int c = i & 1023;
  int hh = c >> 6;
  int e = c & 63;
  dst[i] = src[(size_t)hh * DD * HSS + (size_t)d * HSS + e];
}

// ---------------- layernorm, one block per row of 1024
__global__ __launch_bounds__(256) void ln_kernel(const float* __restrict__ in,
    const float* __restrict__ g, const float* __restrict__ bta, float* __restrict__ out)
{
  __shared__ float sred[8];
  int row = blockIdx.x;
  int tid = threadIdx.x;
  float4 xv = ((const float4*)(in + (size_t)row * DD))[tid];
  float s = xv.x + xv.y + xv.z + xv.w;
  #pragma unroll
  for (int o = 32; o; o >>= 1) s += __shfl_down(s, o);
  if ((tid & 63) == 0) sred[tid >> 6] = s;
  __syncthreads();
  float mean = (sred[0] + sred[1] + sred[2] + sred[3]) * (1.f / DD);
  float d0 = xv.x - mean, d1 = xv.y - mean, d2 = xv.z - mean, d3 = xv.w - mean;
  float sq = d0 * d0 + d1 * d1 + d2 * d2 + d3 * d3;
  #pragma unroll
  for (int o = 32; o; o >>= 1) sq += __shfl_down(sq, o);
  if ((tid & 63) == 0) sred[4 + (tid >> 6)] = sq;
  __syncthreads();
  float var = (sred[4] + sred[5] + sred[6] + sred[7]) * (1.f / DD);
  float inv = rsqrtf(var + 1e-5f);
  float4 gv = ((const float4*)g)[tid];
  float4 bv = ((const float4*)bta)[tid];
  float4 ov = make_float4(d0 * inv * gv.x + bv.x, d1 * inv * gv.y + bv.y,
                          d2 * inv * gv.z + bv.z, d3 * inv * gv.w + bv.w);
  ((float4*)(out + (size_t)row * DD))[tid] = ov;
}

// ---------------- generic f32 GEMM: C[M,N] = A[M,K] @ B[K,N] (+bias)(relu)(+res)
// 64x64 block tile, BK=16, 256 threads, 4x4 per thread.
template<bool RELU, bool BIAS, bool RES>
__global__ __launch_bounds__(256) void gemm_kernel(
    const float* __restrict__ A, const float* __restrict__ Bm,
    const float* __restrict__ bias, const float* __restrict__ res,
    float* __restrict__ C, int M, int N, int K)
{
  __shared__ float As[16][64];   // As[k][m]
  __shared__ float Bs[16][64];   // Bs[k][n]
  const int bm = blockIdx.y * 64, bn = blockIdx.x * 64;
  const int tid = threadIdx.x;
  const int tm = (tid >> 4) << 2;   // 0..60
  const int tn = (tid & 15) << 2;   // 0..60
  const int ar = tid >> 2, ac = (tid & 3) << 2;
  const int br = tid >> 4, bc = (tid & 15) << 2;
  float acc[4][4] = {};
  for (int k0 = 0; k0 < K; k0 += 16) {
    float4 av = *(const float4*)(A + (size_t)(bm + ar) * K + k0 + ac);
    As[ac + 0][ar] = av.x; As[ac + 1][ar] = av.y; As[ac + 2][ar] = av.z; As[ac + 3][ar] = av.w;
    *(float4*)&Bs[br][bc] = *(const float4*)(Bm + (size_t)(k0 + br) * N + bn + bc);
    __syncthreads();
    #pragma unroll
    for (int kk = 0; kk < 16; ++kk) {
      float4 a4 = *(const float4*)&As[kk][tm];
      float4 b4 = *(const float4*)&Bs[kk][tn];
      acc[0][0] += a4.x * b4.x; acc[0][1] += a4.x * b4.y; acc[0][2] += a4.x * b4.z; acc[0][3] += a4.x * b4.w;
      acc[1][0] += a4.y * b4.x; acc[1][1] += a4.y * b4.y; acc[1][2] += a4.y * b4.z; acc[1][3] += a4.y * b4.w;
      acc[2][0] += a4.z * b4.x; acc[2][1] += a4.z * b4.y; acc[2][2] += a4.z * b4.z; acc[2][3] += a4.z * b4.w;
      acc[3][0] += a4.w * b4.x; acc[3][1] += a4.w * b4.y; acc[3][2] += a4.w * b4.z; acc[3][3] += a4.w * b4.w;
    }
    __syncthreads();
  }
  float4 bias4 = make_float4(0.f, 0.f, 0.f, 0.f);
  if (BIAS) bias4 = *(const float4*)(bias + bn + tn);
  #pragma unroll
  for (int i = 0; i < 4; ++i) {
    int row = bm + tm + i;
    float4 v = make_float4(acc[i][0], acc[i][1], acc[i][2], acc[i][3]);
    if (BIAS) { v.x += bias4.x; v.y += bias4.y; v.z += bias4.z; v.w += bias4.w; }
    if (RELU) { v.x = fmaxf(v.x, 0.f); v.y = fmaxf(v.y, 0.f); v.z = fmaxf(v.z, 0.f); v.w = fmaxf(v.w, 0.f); }
    if (RES) {
      float4 r4 = *(const float4*)(res + (size_t)row * N + bn + tn);
      v.x += r4.x; v.y += r4.y; v.z += r4.z; v.w += r4.w;
    }
    *(float4*)(C + (size_t)row * N + bn + tn) = v;
  }
}

// ---------------- cooperative tiled causal attention (f32, flash-style)
// One block = (b, h, 256-row q-tile). 256 threads.
// Thread t: slice s = t&3 (16 HS elems), row-group g = t>>2 -> rows q0+g*4+{0..3}.
// 4 lanes per row; score reduced via shfl_xor(1)+shfl_xor(2).
// K/V staged in LDS in 64-row tiles; online softmax with rescale-on-new-max.
#define QBLK 256
#define KBLK 64
__global__ __launch_bounds__(256, 1) void attn_kernel(const float* __restrict__ qp,
    const float* __restrict__ kp, const float* __restrict__ vp, float* __restrict__ op)
{
  __shared__ float Ks[KBLK][HSS];   // 16 KB
  __shared__ float Vs[KBLK][HSS];   // 16 KB
  const int qt = blockIdx.x & 3;          // q-tile within (b,h)
  const int bh = blockIdx.x >> 2;
  const int b  = bh >> 4;
  const int hh = bh & 15;
  const int q0 = qt * QBLK;
  const int t  = threadIdx.x;
  const int s  = t & 3;                   // HS slice: elems s*16 .. s*16+15
  const int g  = t >> 2;                  // row group 0..63
  const int w  = t >> 6;                  // wave id
  const size_t base = (size_t)b * TT * DD + (size_t)hh * HSS;

  float qr[4][16];
  float acc[4][16];
  float mrow[4], srow[4];
  #pragma unroll
  for (int i = 0; i < 4; ++i) {
    mrow[i] = -3.0e38f; srow[i] = 0.f;
    #pragma unroll
    for (int e = 0; e < 16; ++e) acc[i][e] = 0.f;
    const float4* q4 = (const float4*)(qp + base + (size_t)(q0 + g * 4 + i) * DD + s * 16);
    #pragma unroll
    for (int e4 = 0; e4 < 4; ++e4) {
      float4 xq = q4[e4];
      qr[i][4*e4+0] = xq.x * 0.125f; qr[i][4*e4+1] = xq.y * 0.125f;
      qr[i][4*e4+2] = xq.z * 0.125f; qr[i][4*e4+3] = xq.w * 0.125f;
    }
  }
  const int wave_max = q0 + w * 64 + 63;     // highest row this wave owns
  const int ntiles = (q0 + QBLK) / KBLK;     // block-uniform trip count

  for (int tile = 0; tile < ntiles; ++tile) {
    const int j0 = tile * KBLK;
    __syncthreads();
    #pragma unroll
    for (int i = 0; i < 4; ++i) {           // cooperative K/V tile load (coalesced)
      int idx = i * 256 + t;                // 0..1023 float4 slots
      int rr = idx >> 4, c4 = (idx & 15) * 4;
      *(float4*)&Ks[rr][c4] = *(const float4*)(kp + base + (size_t)(j0 + rr) * DD + c4);
      *(float4*)&Vs[rr][c4] = *(const float4*)(vp + base + (size_t)(j0 + rr) * DD + c4);
    }
    __syncthreads();
    if (j0 <= wave_max) {
      const int jcap = min(KBLK - 1, wave_max - j0);
      for (int jj = 0; jj <= jcap; ++jj) {
        // partial dot over this lane's 16-elem slice, 4 rows
        float part[4] = {0.f, 0.f, 0.f, 0.f};
        #pragma unroll
        for (int e4 = 0; e4 < 4; ++e4) {
          float4 kv = *(const float4*)&Ks[jj][s * 16 + e4 * 4];
          #pragma unroll
          for (int i = 0; i < 4; ++i) {
            part[i] += qr[i][4*e4+0] * kv.x + qr[i][4*e4+1] * kv.y
                     + qr[i][4*e4+2] * kv.z + qr[i][4*e4+3] * kv.w;
          }
        }
        #pragma unroll
        for (int i = 0; i < 4; ++i) {       // reduce across the 4 slice-lanes
          part[i] += __shfl_xor(part[i], 1);
          part[i] += __shfl_xor(part[i], 2);
        }
        const int j = j0 + jj;
        #pragma unroll
        for (int i = 0; i < 4; ++i) {
          const int row = q0 + g * 4 + i;
          float sc = (j <= row) ? part[i] : -3.0e38f;
          if (sc > mrow[i]) {               // new max: rescale (rare)
            float f = __expf(mrow[i] - sc);
            mrow[i] = sc;
            srow[i] *= f;
            #pragma unroll
            for (int e = 0; e < 16; ++e) acc[i][e] *= f;
          }
          float p = __expf(sc - mrow[i]);
          srow[i] += p;
          #pragma unroll
          for (int e4 = 0; e4 < 4; ++e4) {
            float4 vv = *(const float4*)&Vs[jj][s * 16 + e4 * 4];
            acc[i][4*e4+0] += p * vv.x; acc[i][4*e4+1] += p * vv.y;
            acc[i][4*e4+2] += p * vv.z; acc[i][4*e4+3] += p * vv.w;
          }
        }
      }
    }
  }
  #pragma unroll
  for (int i = 0; i < 4; ++i) {
    float inv = 1.f / srow[i];
    float4* o4 = (float4*)(op + base + (size_t)(q0 + g * 4 + i) * DD + s * 16);
    #pragma unroll
    for (int e4 = 0; e4 < 4; ++e4)
      o4[e4] = make_float4(acc[i][4*e4+0] * inv, acc[i][4*e4+1] * inv,
                           acc[i][4*e4+2] * inv, acc[i][4*e4+3] * inv);
  }
}

extern "C" void kernel_launch(void* const* d_in, const int* in_sizes, int n_in,
                              void* d_out, int out_size, void* d_ws, size_t ws_size,
                              hipStream_t stream)
{
  const int*   x     = (const int*)d_in[0];
  const float* tok   = (const float*)d_in[1];
  const float* pos   = (const float*)d_in[2];
  const float* wq    = (const float*)d_in[3];
  const float* wk    = (const float*)d_in[4];
  const float* wv    = (const float*)d_in[5];
  const float* w_o   = (const float*)d_in[6];
  const float* b_o   = (const float*)d_in[7];
  const float* ln1_g = (const float*)d_in[8];
  const float* ln1_b = (const float*)d_in[9];
  const float* ln2_g = (const float*)d_in[10];
  const float* ln2_b = (const float*)d_in[11];
  const float* w1    = (const float*)d_in[12];
  const float* b1    = (const float*)d_in[13];
  const float* w2    = (const float*)d_in[14];
  const float* b2    = (const float*)d_in[15];
  const float* lnf_g = (const float*)d_in[16];
  const float* lnf_b = (const float*)d_in[17];
  const float* w_lm  = (const float*)d_in[18];
  const float* b_lm  = (const float*)d_in[19];
  float* out = (float*)d_out;
  float* ws  = (float*)d_ws;

  const size_t MD = (size_t)MM * DD;          // 4M floats
  float* h   = ws;                            // 4M
  float* hn  = ws + MD;                       // 4M
  float* q   = ws + 2 * MD;                   // 4M
  float* kb  = ws + 3 * MD;                   // 4M
  float* vb  = ws + 4 * MD;                   // 4M
  float* ob  = ws + 5 * MD;                   // 4M
  float* mlp = ws + 2 * MD;                   // 16M, overlays q/kb/vb/ob (dead by then)
  float* wp0 = ws + 6 * MD;                   // 1M each
  float* wp1 = wp0 + (size_t)DD * HH * HSS;
  float* wp2 = wp1 + (size_t)DD * HH * HSS;

  embed_kernel<<<dim3(MM * DD / 4 / 256), 256, 0, stream>>>(x, tok, pos, h);

  for (int l = 0; l < LL; ++l) {
    ln_kernel<<<MM, 256, 0, stream>>>(h, ln1_g + (size_t)l * DD, ln1_b + (size_t)l * DD, hn);
    size_t woff = (size_t)l * HH * DD * HSS;
    repack_kernel<<<4096, 256, 0, stream>>>(wq + woff, wp0);
    repack_kernel<<<4096, 256, 0, stream>>>(wk + woff, wp1);
    repack_kernel<<<4096, 256, 0, stream>>>(wv + woff, wp2);
    gemm_kernel<false,false,false><<<dim3(16, 64), 256, 0, stream>>>(hn, wp0, nullptr, nullptr, q,  MM, DD, DD);
    gemm_kernel<false,false,false><<<dim3(16, 64), 256, 0, stream>>>(hn, wp1, nullptr, nullptr, kb, MM, DD, DD);
    gemm_kernel<false,false,false><<<dim3(16, 64), 256, 0, stream>>>(hn, wp2, nullptr, nullptr, vb, MM, DD, DD);
    attn_kernel<<<dim3(BB * HH * (TT / QBLK)), 256, 0, stream>>>(q, kb, vb, ob);
    gemm_kernel<false,true,true><<<dim3(16, 64), 256, 0, stream>>>(ob, w_o + (size_t)l * HH * HSS * DD,
                                                                   b_o + (size_t)l * DD, hn, h, MM, DD, DD);
    ln_kernel<<<MM, 256, 0, stream>>>(h, ln2_g + (size_t)l * DD, ln2_b + (size_t)l * DD, hn);
    gemm_kernel<true,true,false><<<dim3(64, 64), 256, 0, stream>>>(hn, w1 + (size_t)l * DD * FFD,
                                                                   b1 + (size_t)l * FFD, nullptr, mlp, MM, FFD, DD);
    gemm_kernel<false,true,true><<<dim3(16, 64), 256, 0, stream>>>(mlp, w2 + (size_t)l * FFD * DD,
                                                                   b2 + (size_t)l * DD, hn, h, MM, DD, FFD);
  }
  ln_kernel<<<MM, 256, 0, stream>>>(h, lnf_g, lnf_b, hn);
  gemm_kernel<false,true,false><<<dim3(VV / 64, MM / 64), 256, 0, stream>>>(hn, w_lm, b_lm, nullptr, out, MM, VV, DD);
}

// Round 3
// 6142.150 us; speedup vs baseline: 4.4156x; 2.9042x over previous
//
#include <hip/hip_runtime.h>
#include <hip/hip_bf16.h>
#include <math.h>

#define BB 4
#define TT 1024
#define DD 1024
#define HH 16
#define HSS 64
#define LL 8
#define VV 8192
#define FFD 4096
#define MM (BB*TT)   // 4096 rows
#define ASTR 3072    // fused qkv row stride

typedef __attribute__((ext_vector_type(8))) _Float16 f16x8;
typedef __attribute__((ext_vector_type(4))) _Float16 f16x4;
typedef __attribute__((ext_vector_type(4))) float floatx4;

// async global->LDS, 16B per lane; LDS dest is wave-uniform base + lane*16
__device__ __forceinline__ void gload_lds16(const void* g, void* l) {
  __builtin_amdgcn_global_load_lds(
      (const __attribute__((address_space(1))) void*)(uintptr_t)g,
      (__attribute__((address_space(3))) void*)(uintptr_t)l, 16, 0, 0);
}

// ---------------- embedding: h = tok[x] + pos[x]  (pos indexed by TOKEN id - reference quirk)
__global__ __launch_bounds__(256) void embed_kernel(const int* __restrict__ x,
    const float* __restrict__ tok, const float* __restrict__ pos, float* __restrict__ h)
{
  int i = blockIdx.x * 256 + threadIdx.x;
  int row = i >> 8;
  int c4 = i & 255;
  int id = x[row];
  float4 a = ((const float4*)(tok + (size_t)id * DD))[c4];
  float4 b = ((const float4*)(pos + (size_t)id * DD))[c4];
  ((float4*)(h + (size_t)row * DD))[c4] = make_float4(a.x + b.x, a.y + b.y, a.z + b.z, a.w + b.w);
}

// ---------------- qkv weight prep: wq/wk/wv (H,D,HS) f32 -> fused BT [3072][1024] f16
__global__ __launch_bounds__(256) void prep_qkv(const float* __restrict__ wq,
    const float* __restrict__ wk, const float* __restrict__ wv, _Float16* __restrict__ bt)
{
  int i = blockIdx.x * 256 + threadIdx.x;   // 3*1024*1024
  int n = i >> 10, d = i & 1023;
  int m = n >> 10;
  int nn = n & 1023;
  int hh = nn >> 6, e = nn & 63;
  const float* src = (m == 0) ? wq : (m == 1) ? wk : wv;
  bt[i] = (_Float16)src[((size_t)hh * DD + d) * HSS + e];
}

// ---------------- transpose+cvt: in f32 [K][N] -> out f16 [N][K]; 64x64 LDS tiles
__global__ __launch_bounds__(256) void tcvt(const float* __restrict__ in,
    _Float16* __restrict__ out, int K, int N)
{
  __shared__ float tile[64][65];
  int bk = blockIdx.x * 64, bn = blockIdx.y * 64;
  int r = threadIdx.x >> 4, c4 = (threadIdx.x & 15) << 2;
  #pragma unroll
  for (int p = 0; p < 4; ++p) {
    float4 v = *(const float4*)(in + (size_t)(bk + p * 16 + r) * N + bn + c4);
    tile[p * 16 + r][c4 + 0] = v.x; tile[p * 16 + r][c4 + 1] = v.y;
    tile[p * 16 + r][c4 + 2] = v.z; tile[p * 16 + r][c4 + 3] = v.w;
  }
  __syncthreads();
  #pragma unroll
  for (int p = 0; p < 4; ++p) {
    int n = p * 16 + r;
    f16x4 o;
    o[0] = (_Float16)tile[c4 + 0][n]; o[1] = (_Float16)tile[c4 + 1][n];
    o[2] = (_Float16)tile[c4 + 2][n]; o[3] = (_Float16)tile[c4 + 3][n];
    *(f16x4*)(out + (size_t)(bn + n) * K + bk + c4) = o;
  }
}

// ---------------- layernorm: writes f32 (residual use) + f16 (GEMM A operand)
__global__ __launch_bounds__(256) void ln_kernel(const float* __restrict__ in,
    const float* __restrict__ g, const float* __restrict__ bta,
    float* __restrict__ out, _Float16* __restrict__ out16)
{
  __shared__ float sred[8];
  int row = blockIdx.x;
  int tid = threadIdx.x;
  float4 xv = ((const float4*)(in + (size_t)row * DD))[tid];
  float s = xv.x + xv.y + xv.z + xv.w;
  #pragma unroll
  for (int o = 32; o; o >>= 1) s += __shfl_down(s, o);
  if ((tid & 63) == 0) sred[tid >> 6] = s;
  __syncthreads();
  float mean = (sred[0] + sred[1] + sred[2] + sred[3]) * (1.f / DD);
  float d0 = xv.x - mean, d1 = xv.y - mean, d2 = xv.z - mean, d3 = xv.w - mean;
  float sq = d0 * d0 + d1 * d1 + d2 * d2 + d3 * d3;
  #pragma unroll
  for (int o = 32; o; o >>= 1) sq += __shfl_down(sq, o);
  if ((tid & 63) == 0) sred[4 + (tid >> 6)] = sq;
  __syncthreads();
  float var = (sred[4] + sred[5] + sred[6] + sred[7]) * (1.f / DD);
  float inv = rsqrtf(var + 1e-5f);
  float4 gv = ((const float4*)g)[tid];
  float4 bv = ((const float4*)bta)[tid];
  float4 ov = make_float4(d0 * inv * gv.x + bv.x, d1 * inv * gv.y + bv.y,
                          d2 * inv * gv.z + bv.z, d3 * inv * gv.w + bv.w);
  ((float4*)(out + (size_t)row * DD))[tid] = ov;
  f16x4 o16;
  o16[0] = (_Float16)ov.x; o16[1] = (_Float16)ov.y;
  o16[2] = (_Float16)ov.z; o16[3] = (_Float16)ov.w;
  *(f16x4*)(out16 + (size_t)row * DD + tid * 4) = o16;
}

// ---------------- MFMA f16 GEMM: C[M,N] = A[M,K] @ Bt[N,K]^T (+bias)(relu)(+res)
// m97 structure: 128x128 tile, BK=64, 4 waves (2x2 of 64x64), global_load_lds w16,
// T2 XOR-swizzle (linear LDS dest + inverse-swizzled global src + swizzled read).
#define GBM 128
#define GBN 128
#define GBK 64
template<bool OUT16, bool RELU, bool BIAS, bool RES>
__global__ __launch_bounds__(256) void mfma_gemm(
    const _Float16* __restrict__ A, const _Float16* __restrict__ Bt,
    const float* __restrict__ bias, const float* __restrict__ res,
    void* __restrict__ Cout, int M, int N, int K)
{
  __shared__ __align__(16) _Float16 Asl[GBM * GBK];   // 16 KB, row stride 128 B
  __shared__ __align__(16) _Float16 Bsl[GBN * GBK];   // 16 KB
  const int tid = threadIdx.x;
  const int w = tid >> 6, l = tid & 63;
  const int bm = blockIdx.y * GBM, bn = blockIdx.x * GBN;
  const int wr = (w >> 1) * 64, wc = (w & 1) * 64;
  const int srow = l >> 3;            // 0..7: row within 8-row staging group
  const int scol = l & 7;             // 16B chunk within 128B row

  floatx4 acc[4][4];
  #pragma unroll
  for (int mi = 0; mi < 4; ++mi)
    #pragma unroll
    for (int ni = 0; ni < 4; ++ni) acc[mi][ni] = (floatx4){0.f, 0.f, 0.f, 0.f};

  for (int k0 = 0; k0 < K; k0 += GBK) {
    __syncthreads();                  // previous iter's readers done
    #pragma unroll
    for (int i = 0; i < 4; ++i) {
      int rA = w * 32 + i * 8 + srow;                     // LDS row 0..127
      // inverse-swizzled global source: LDS[row][b] holds G[row][b ^ ((row&7)<<4)]
      const void* gpA = (const char*)(A + (size_t)(bm + rA) * K + k0) + ((scol ^ srow) << 4);
      gload_lds16(gpA, (void*)&Asl[(size_t)(w * 32 + i * 8) * GBK]);
      const void* gpB = (const char*)(Bt + (size_t)(bn + rA) * K + k0) + ((scol ^ srow) << 4);
      gload_lds16(gpB, (void*)&Bsl[(size_t)(w * 32 + i * 8) * GBK]);
    }
    __syncthreads();                  // drains vmcnt(0) + barrier
    #pragma unroll
    for (int kk = 0; kk < 2; ++kk) {
      const int kbyte = kk * 64 + (l >> 4) * 16;
      f16x8 af[4], bf[4];
      #pragma unroll
      for (int mi = 0; mi < 4; ++mi) {
        int row = wr + mi * 16 + (l & 15);
        af[mi] = *(const f16x8*)((const char*)Asl + row * 128 + (kbyte ^ ((row & 7) << 4)));
      }
      #pragma unroll
      for (int ni = 0; ni < 4; ++ni) {
        int row = wc + ni * 16 + (l & 15);
        bf[ni] = *(const f16x8*)((const char*)Bsl + row * 128 + (kbyte ^ ((row & 7) << 4)));
      }
      #pragma unroll
      for (int mi = 0; mi < 4; ++mi)
        #pragma unroll
        for (int ni = 0; ni < 4; ++ni)
          acc[mi][ni] = __builtin_amdgcn_mfma_f32_16x16x32_f16(af[mi], bf[ni], acc[mi][ni], 0, 0, 0);
    }
  }

  // epilogue: C/D layout col=lane&15, row=(lane>>4)*4+reg  [m91-verified]
  #pragma unroll
  for (int ni = 0; ni < 4; ++ni) {
    const int col = bn + wc + ni * 16 + (l & 15);
    const float bv = BIAS ? bias[col] : 0.f;
    #pragma unroll
    for (int mi = 0; mi < 4; ++mi) {
      #pragma unroll
      for (int r = 0; r < 4; ++r) {
        const int row = bm + wr + mi * 16 + (l >> 4) * 4 + r;
        float v = acc[mi][ni][r] + bv;
        if (RELU) v = fmaxf(v, 0.f);
        if (RES) v += res[(size_t)row * N + col];
        if (OUT16) ((_Float16*)Cout)[(size_t)row * N + col] = (_Float16)v;
        else       ((float*)Cout)[(size_t)row * N + col] = v;
      }
    }
  }
}

// ---------------- cooperative tiled causal attention (f32 in from fused qkv, f16 out)
#define QBLK 256
#define KBLK 64
__global__ __launch_bounds__(256, 1) void attn_kernel(const float* __restrict__ qkv,
    _Float16* __restrict__ op)
{
  __shared__ float Ks[KBLK][HSS];
  __shared__ float Vs[KBLK][HSS];
  const int qt = blockIdx.x & 3;
  const int bh = blockIdx.x >> 2;
  const int b  = bh >> 4;
  const int hh = bh & 15;
  const int q0 = qt * QBLK;
  const int t  = threadIdx.x;
  const int s  = t & 3;
  const int g  = t >> 2;
  const int w  = t >> 6;
  const size_t rowbase = (size_t)b * TT;
  const int hoff = hh * HSS;

  float qr[4][16];
  float acc[4][16];
  float mrow[4], srow[4];
  #pragma unroll
  for (int i = 0; i < 4; ++i) {
    mrow[i] = -3.0e38f; srow[i] = 0.f;
    #pragma unroll
    for (int e = 0; e < 16; ++e) acc[i][e] = 0.f;
    const float4* q4 = (const float4*)(qkv + (rowbase + q0 + g * 4 + i) * ASTR + hoff + s * 16);
    #pragma unroll
    for (int e4 = 0; e4 < 4; ++e4) {
      float4 xq = q4[e4];
      qr[i][4*e4+0] = xq.x * 0.125f; qr[i][4*e4+1] = xq.y * 0.125f;
      qr[i][4*e4+2] = xq.z * 0.125f; qr[i][4*e4+3] = xq.w * 0.125f;
    }
  }
  const int wave_max = q0 + w * 64 + 63;
  const int ntiles = (q0 + QBLK) / KBLK;

  for (int tile = 0; tile < ntiles; ++tile) {
    const int j0 = tile * KBLK;
    __syncthreads();
    #pragma unroll
    for (int i = 0; i < 4; ++i) {
      int idx = i * 256 + t;
      int rr = idx >> 4, c4 = (idx & 15) * 4;
      *(float4*)&Ks[rr][c4] = *(const float4*)(qkv + (rowbase + j0 + rr) * ASTR + 1024 + hoff + c4);
      *(float4*)&Vs[rr][c4] = *(const float4*)(qkv + (rowbase + j0 + rr) * ASTR + 2048 + hoff + c4);
    }
    __syncthreads();
    if (j0 <= wave_max) {
      const int jcap = min(KBLK - 1, wave_max - j0);
      for (int jj = 0; jj <= jcap; ++jj) {
        float part[4] = {0.f, 0.f, 0.f, 0.f};
        #pragma unroll
        for (int e4 = 0; e4 < 4; ++e4) {
          float4 kv = *(const float4*)&Ks[jj][s * 16 + e4 * 4];
          #pragma unroll
          for (int i = 0; i < 4; ++i) {
            part[i] += qr[i][4*e4+0] * kv.x + qr[i][4*e4+1] * kv.y
                     + qr[i][4*e4+2] * kv.z + qr[i][4*e4+3] * kv.w;
          }
        }
        #pragma unroll
        for (int i = 0; i < 4; ++i) {
          part[i] += __shfl_xor(part[i], 1);
          part[i] += __shfl_xor(part[i], 2);
        }
        const int j = j0 + jj;
        #pragma unroll
        for (int i = 0; i < 4; ++i) {
          const int row = q0 + g * 4 + i;
          float sc = (j <= row) ? part[i] : -3.0e38f;
          if (sc > mrow[i]) {
            float f = __expf(mrow[i] - sc);
            mrow[i] = sc;
            srow[i] *= f;
            #pragma unroll
            for (int e = 0; e < 16; ++e) acc[i][e] *= f;
          }
          float p = __expf(sc - mrow[i]);
          srow[i] += p;
          #pragma unroll
          for (int e4 = 0; e4 < 4; ++e4) {
            float4 vv = *(const float4*)&Vs[jj][s * 16 + e4 * 4];
            acc[i][4*e4+0] += p * vv.x; acc[i][4*e4+1] += p * vv.y;
            acc[i][4*e4+2] += p * vv.z; acc[i][4*e4+3] += p * vv.w;
          }
        }
      }
    }
  }
  #pragma unroll
  for (int i = 0; i < 4; ++i) {
    float inv = 1.f / srow[i];
    _Float16* od = op + (rowbase + q0 + g * 4 + i) * (size_t)DD + hoff + s * 16;
    #pragma unroll
    for (int e4 = 0; e4 < 4; ++e4) {
      f16x4 o4;
      o4[0] = (_Float16)(acc[i][4*e4+0] * inv); o4[1] = (_Float16)(acc[i][4*e4+1] * inv);
      o4[2] = (_Float16)(acc[i][4*e4+2] * inv); o4[3] = (_Float16)(acc[i][4*e4+3] * inv);
      *(f16x4*)(od + e4 * 4) = o4;
    }
  }
}

extern "C" void kernel_launch(void* const* d_in, const int* in_sizes, int n_in,
                              void* d_out, int out_size, void* d_ws, size_t ws_size,
                              hipStream_t stream)
{
  const int*   x     = (const int*)d_in[0];
  const float* tok   = (const float*)d_in[1];
  const float* pos   = (const float*)d_in[2];
  const float* wq    = (const float*)d_in[3];
  const float* wk    = (const float*)d_in[4];
  const float* wv    = (const float*)d_in[5];
  const float* w_o   = (const float*)d_in[6];
  const float* b_o   = (const float*)d_in[7];
  const float* ln1_g = (const float*)d_in[8];
  const float* ln1_b = (const float*)d_in[9];
  const float* ln2_g = (const float*)d_in[10];
  const float* ln2_b = (const float*)d_in[11];
  const float* w1    = (const float*)d_in[12];
  const float* b1    = (const float*)d_in[13];
  const float* w2    = (const float*)d_in[14];
  const float* b2    = (const float*)d_in[15];
  const float* lnf_g = (const float*)d_in[16];
  const float* lnf_b = (const float*)d_in[17];
  const float* w_lm  = (const float*)d_in[18];
  const float* b_lm  = (const float*)d_in[19];
  float* out = (float*)d_out;
  char* p = (char*)d_ws;

  const size_t MB = 1024 * 1024;
  float*    h      = (float*)(p);                 // 16 MB
  float*    hn     = (float*)(p + 16 * MB);       // 16 MB
  _Float16* hn16   = (_Float16*)(p + 32 * MB);    // 8 MB
  float*    qkv    = (float*)(p + 40 * MB);       // 48 MB
  _Float16* mlp16  = (_Float16*)(p + 40 * MB);    // 32 MB (overlays qkv, dead post-attn)
  _Float16* wlm_t  = (_Float16*)(p + 72 * MB);    // 16 MB (overlays qkv tail, used after loop)
  _Float16* ob16   = (_Float16*)(p + 88 * MB);    // 8 MB
  _Float16* wqkv_t = (_Float16*)(p + 96 * MB);    // 6 MB
  _Float16* wo_t   = (_Float16*)(p + 102 * MB);   // 2 MB
  _Float16* w1_t   = (_Float16*)(p + 104 * MB);   // 8 MB
  _Float16* w2_t   = (_Float16*)(p + 112 * MB);   // 8 MB  -> total 120 MB

  embed_kernel<<<dim3(MM * DD / 4 / 256), 256, 0, stream>>>(x, tok, pos, h);

  for (int l = 0; l < LL; ++l) {
    const size_t wqo = (size_t)l * HH * DD * HSS;       // 1M
    const size_t woo = (size_t)l * HH * HSS * DD;       // 1M
    ln_kernel<<<MM, 256, 0, stream>>>(h, ln1_g + (size_t)l * DD, ln1_b + (size_t)l * DD, hn, hn16);
    prep_qkv<<<3 * 1024 * 1024 / 256, 256, 0, stream>>>(wq + wqo, wk + wqo, wv + wqo, wqkv_t);
    mfma_gemm<false,false,false,false><<<dim3(ASTR / GBN, MM / GBM), 256, 0, stream>>>(
        hn16, wqkv_t, nullptr, nullptr, qkv, MM, ASTR, DD);
    attn_kernel<<<dim3(BB * HH * (TT / QBLK)), 256, 0, stream>>>(qkv, ob16);
    tcvt<<<dim3(16, 16), 256, 0, stream>>>(w_o + woo, wo_t, DD, DD);
    mfma_gemm<false,false,true,true><<<dim3(DD / GBN, MM / GBM), 256, 0, stream>>>(
        ob16, wo_t, b_o + (size_t)l * DD, hn, h, MM, DD, DD);
    ln_kernel<<<MM, 256, 0, stream>>>(h, ln2_g + (size_t)l * DD, ln2_b + (size_t)l * DD, hn, hn16);
    tcvt<<<dim3(16, 64), 256, 0, stream>>>(w1 + (size_t)l * DD * FFD, w1_t, DD, FFD);
    mfma_gemm<true,true,true,false><<<dim3(FFD / GBN, MM / GBM), 256, 0, stream>>>(
        hn16, w1_t, b1 + (size_t)l * FFD, nullptr, mlp16, MM, FFD, DD);
    tcvt<<<dim3(64, 16), 256, 0, stream>>>(w2 + (size_t)l * FFD * DD, w2_t, FFD, DD);
    mfma_gemm<false,false,true,true><<<dim3(DD / GBN, MM / GBM), 256, 0, stream>>>(
        mlp16, w2_t, b2 + (size_t)l * DD, hn, h, MM, DD, FFD);
  }
  ln_kernel<<<MM, 256, 0, stream>>>(h, lnf_g, lnf_b, hn, hn16);
  tcvt<<<dim3(16, 128), 256, 0, stream>>>(w_lm, wlm_t, DD, VV);
  mfma_gemm<false,false,true,false><<<dim3(VV / GBN, MM / GBM), 256, 0, stream>>>(
      hn16, wlm_t, b_lm, nullptr, out, MM, VV, DD);
}

// Round 4
// 5041.804 us; speedup vs baseline: 5.3793x; 1.2182x over previous
//
#include <hip/hip_runtime.h>
#include <hip/hip_bf16.h>
#include <math.h>

#define BB 4
#define TT 1024
#define DD 1024
#define HH 16
#define HSS 64
#define LL 8
#define VV 8192
#define FFD 4096
#define MM (BB*TT)   // 4096 rows
#define ASTR 3072    // fused qkv row stride

typedef __attribute__((ext_vector_type(8))) _Float16 f16x8;
typedef __attribute__((ext_vector_type(4))) _Float16 f16x4;
typedef __attribute__((ext_vector_type(4))) float floatx4;

// async global->LDS, 16B per lane; LDS dest is wave-uniform base + lane*16
__device__ __forceinline__ void gload_lds16(const void* g, void* l) {
  __builtin_amdgcn_global_load_lds(
      (const __attribute__((address_space(1))) void*)(uintptr_t)g,
      (__attribute__((address_space(3))) void*)(uintptr_t)l, 16, 0, 0);
}

// ---------------- embedding: h = tok[x] + pos[x]  (pos indexed by TOKEN id - reference quirk)
__global__ __launch_bounds__(256) void embed_kernel(const int* __restrict__ x,
    const float* __restrict__ tok, const float* __restrict__ pos, float* __restrict__ h)
{
  int i = blockIdx.x * 256 + threadIdx.x;
  int row = i >> 8;
  int c4 = i & 255;
  int id = x[row];
  float4 a = ((const float4*)(tok + (size_t)id * DD))[c4];
  float4 b = ((const float4*)(pos + (size_t)id * DD))[c4];
  ((float4*)(h + (size_t)row * DD))[c4] = make_float4(a.x + b.x, a.y + b.y, a.z + b.z, a.w + b.w);
}

// ---------------- qkv weight prep: wq/wk/wv (H,D,HS) f32 -> fused BT [3072][1024] f16
__global__ __launch_bounds__(256) void prep_qkv(const float* __restrict__ wq,
    const float* __restrict__ wk, const float* __restrict__ wv, _Float16* __restrict__ bt)
{
  int i = blockIdx.x * 256 + threadIdx.x;   // 3*1024*1024
  int n = i >> 10, d = i & 1023;
  int m = n >> 10;
  int nn = n & 1023;
  int hh = nn >> 6, e = nn & 63;
  const float* src = (m == 0) ? wq : (m == 1) ? wk : wv;
  bt[i] = (_Float16)src[((size_t)hh * DD + d) * HSS + e];
}

// ---------------- transpose+cvt: in f32 [K][N] -> out f16 [N][K]; 64x64 LDS tiles
__global__ __launch_bounds__(256) void tcvt(const float* __restrict__ in,
    _Float16* __restrict__ out, int K, int N)
{
  __shared__ float tile[64][65];
  int bk = blockIdx.x * 64, bn = blockIdx.y * 64;
  int r = threadIdx.x >> 4, c4 = (threadIdx.x & 15) << 2;
  #pragma unroll
  for (int p = 0; p < 4; ++p) {
    float4 v = *(const float4*)(in + (size_t)(bk + p * 16 + r) * N + bn + c4);
    tile[p * 16 + r][c4 + 0] = v.x; tile[p * 16 + r][c4 + 1] = v.y;
    tile[p * 16 + r][c4 + 2] = v.z; tile[p * 16 + r][c4 + 3] = v.w;
  }
  __syncthreads();
  #pragma unroll
  for (int p = 0; p < 4; ++p) {
    int n = p * 16 + r;
    f16x4 o;
    o[0] = (_Float16)tile[c4 + 0][n]; o[1] = (_Float16)tile[c4 + 1][n];
    o[2] = (_Float16)tile[c4 + 2][n]; o[3] = (_Float16)tile[c4 + 3][n];
    *(f16x4*)(out + (size_t)(bn + n) * K + bk + c4) = o;
  }
}

// ---------------- layernorm: writes f32 (residual use) + f16 (GEMM A operand)
__global__ __launch_bounds__(256) void ln_kernel(const float* __restrict__ in,
    const float* __restrict__ g, const float* __restrict__ bta,
    float* __restrict__ out, _Float16* __restrict__ out16)
{
  __shared__ float sred[8];
  int row = blockIdx.x;
  int tid = threadIdx.x;
  float4 xv = ((const float4*)(in + (size_t)row * DD))[tid];
  float s = xv.x + xv.y + xv.z + xv.w;
  #pragma unroll
  for (int o = 32; o; o >>= 1) s += __shfl_down(s, o);
  if ((tid & 63) == 0) sred[tid >> 6] = s;
  __syncthreads();
  float mean = (sred[0] + sred[1] + sred[2] + sred[3]) * (1.f / DD);
  float d0 = xv.x - mean, d1 = xv.y - mean, d2 = xv.z - mean, d3 = xv.w - mean;
  float sq = d0 * d0 + d1 * d1 + d2 * d2 + d3 * d3;
  #pragma unroll
  for (int o = 32; o; o >>= 1) sq += __shfl_down(sq, o);
  if ((tid & 63) == 0) sred[4 + (tid >> 6)] = sq;
  __syncthreads();
  float var = (sred[4] + sred[5] + sred[6] + sred[7]) * (1.f / DD);
  float inv = rsqrtf(var + 1e-5f);
  float4 gv = ((const float4*)g)[tid];
  float4 bv = ((const float4*)bta)[tid];
  float4 ov = make_float4(d0 * inv * gv.x + bv.x, d1 * inv * gv.y + bv.y,
                          d2 * inv * gv.z + bv.z, d3 * inv * gv.w + bv.w);
  ((float4*)(out + (size_t)row * DD))[tid] = ov;
  f16x4 o16;
  o16[0] = (_Float16)ov.x; o16[1] = (_Float16)ov.y;
  o16[2] = (_Float16)ov.z; o16[3] = (_Float16)ov.w;
  *(f16x4*)(out16 + (size_t)row * DD + tid * 4) = o16;
}

// ---------------- MFMA f16 GEMM: C[M,N] = A[M,K] @ Bt[N,K]^T (+bias)(relu)(+res)
// m97 structure: 128x128 tile, BK=64, 4 waves (2x2 of 64x64), global_load_lds w16,
// T2 XOR-swizzle (linear LDS dest + inverse-swizzled global src + swizzled read).
#define GBM 128
#define GBN 128
#define GBK 64
template<bool OUT16, bool RELU, bool BIAS, bool RES>
__global__ __launch_bounds__(256) void mfma_gemm(
    const _Float16* __restrict__ A, const _Float16* __restrict__ Bt,
    const float* __restrict__ bias, const float* __restrict__ res,
    void* __restrict__ Cout, int M, int N, int K)
{
  __shared__ __align__(16) _Float16 Asl[GBM * GBK];   // 16 KB, row stride 128 B
  __shared__ __align__(16) _Float16 Bsl[GBN * GBK];   // 16 KB
  const int tid = threadIdx.x;
  const int w = tid >> 6, l = tid & 63;
  const int bm = blockIdx.y * GBM, bn = blockIdx.x * GBN;
  const int wr = (w >> 1) * 64, wc = (w & 1) * 64;
  const int srow = l >> 3;            // 0..7: row within 8-row staging group
  const int scol = l & 7;             // 16B chunk within 128B row

  floatx4 acc[4][4];
  #pragma unroll
  for (int mi = 0; mi < 4; ++mi)
    #pragma unroll
    for (int ni = 0; ni < 4; ++ni) acc[mi][ni] = (floatx4){0.f, 0.f, 0.f, 0.f};

  for (int k0 = 0; k0 < K; k0 += GBK) {
    __syncthreads();                  // previous iter's readers done
    #pragma unroll
    for (int i = 0; i < 4; ++i) {
      int rA = w * 32 + i * 8 + srow;                     // LDS row 0..127
      // inverse-swizzled global source: LDS[row][b] holds G[row][b ^ ((row&7)<<4)]
      const void* gpA = (const char*)(A + (size_t)(bm + rA) * K + k0) + ((scol ^ srow) << 4);
      gload_lds16(gpA, (void*)&Asl[(size_t)(w * 32 + i * 8) * GBK]);
      const void* gpB = (const char*)(Bt + (size_t)(bn + rA) * K + k0) + ((scol ^ srow) << 4);
      gload_lds16(gpB, (void*)&Bsl[(size_t)(w * 32 + i * 8) * GBK]);
    }
    __syncthreads();                  // drains vmcnt(0) + barrier
    #pragma unroll
    for (int kk = 0; kk < 2; ++kk) {
      const int kbyte = kk * 64 + (l >> 4) * 16;
      f16x8 af[4], bf[4];
      #pragma unroll
      for (int mi = 0; mi < 4; ++mi) {
        int row = wr + mi * 16 + (l & 15);
        af[mi] = *(const f16x8*)((const char*)Asl + row * 128 + (kbyte ^ ((row & 7) << 4)));
      }
      #pragma unroll
      for (int ni = 0; ni < 4; ++ni) {
        int row = wc + ni * 16 + (l & 15);
        bf[ni] = *(const f16x8*)((const char*)Bsl + row * 128 + (kbyte ^ ((row & 7) << 4)));
      }
      #pragma unroll
      for (int mi = 0; mi < 4; ++mi)
        #pragma unroll
        for (int ni = 0; ni < 4; ++ni)
          acc[mi][ni] = __builtin_amdgcn_mfma_f32_16x16x32_f16(af[mi], bf[ni], acc[mi][ni], 0, 0, 0);
    }
  }

  // epilogue: C/D layout col=lane&15, row=(lane>>4)*4+reg  [m91-verified]
  #pragma unroll
  for (int ni = 0; ni < 4; ++ni) {
    const int col = bn + wc + ni * 16 + (l & 15);
    const float bv = BIAS ? bias[col] : 0.f;
    #pragma unroll
    for (int mi = 0; mi < 4; ++mi) {
      #pragma unroll
      for (int r = 0; r < 4; ++r) {
        const int row = bm + wr + mi * 16 + (l >> 4) * 4 + r;
        float v = acc[mi][ni][r] + bv;
        if (RELU) v = fmaxf(v, 0.f);
        if (RES) v += res[(size_t)row * N + col];
        if (OUT16) ((_Float16*)Cout)[(size_t)row * N + col] = (_Float16)v;
        else       ((float*)Cout)[(size_t)row * N + col] = v;
      }
    }
  }
}

// ---------------- cooperative tiled causal attention (f32, flash-style)
// One block = (b, h, 64-row q-tile), 256 threads, one thread per q-row
// (4 slice-lanes x 16 elems). Tiles 0..qt-1 need no mask; diagonal tile
// loops jj<=g per-thread (jj<=g <=> j<=row), so no compare/select at all.
#define QBLK 64
#define KBLK 64
__global__ __launch_bounds__(256) void attn_kernel(const float* __restrict__ qkv,
    _Float16* __restrict__ op)
{
  __shared__ float Ks[KBLK][HSS];   // 16 KB
  __shared__ float Vs[KBLK][HSS];   // 16 KB
  const int qt = blockIdx.x & 15;         // q-tile within (b,h): 16 tiles of 64
  const int bh = blockIdx.x >> 4;
  const int b  = bh >> 4;
  const int hh = bh & 15;
  const int q0 = qt * QBLK;
  const int t  = threadIdx.x;
  const int s  = t & 3;                   // HS slice: elems s*16 .. s*16+15
  const int g  = t >> 2;                  // q-row within tile, 0..63
  const size_t rowbase = (size_t)b * TT;
  const int hoff = hh * HSS;

  float qr[16], acc[16];
  float m = -3.0e38f, sum = 0.f;
  #pragma unroll
  for (int e = 0; e < 16; ++e) acc[e] = 0.f;
  {
    const float4* q4 = (const float4*)(qkv + (rowbase + q0 + g) * ASTR + hoff + s * 16);
    #pragma unroll
    for (int e4 = 0; e4 < 4; ++e4) {
      float4 xq = q4[e4];
      qr[4*e4+0] = xq.x * 0.125f; qr[4*e4+1] = xq.y * 0.125f;
      qr[4*e4+2] = xq.z * 0.125f; qr[4*e4+3] = xq.w * 0.125f;
    }
  }

  for (int tile = 0; tile <= qt; ++tile) {
    const int j0 = tile * KBLK;
    __syncthreads();
    #pragma unroll
    for (int i = 0; i < 4; ++i) {         // cooperative K/V tile load (coalesced)
      int idx = i * 256 + t;              // 0..1023 float4 slots
      int rr = idx >> 4, c4 = (idx & 15) * 4;
      *(float4*)&Ks[rr][c4] = *(const float4*)(qkv + (rowbase + j0 + rr) * ASTR + 1024 + hoff + c4);
      *(float4*)&Vs[rr][c4] = *(const float4*)(qkv + (rowbase + j0 + rr) * ASTR + 2048 + hoff + c4);
    }
    __syncthreads();
    const int jcap = (tile < qt) ? (KBLK - 1) : g;
    for (int jj = 0; jj <= jcap; ++jj) {
      float part = 0.f;
      #pragma unroll
      for (int e4 = 0; e4 < 4; ++e4) {
        float4 kv = *(const float4*)&Ks[jj][s * 16 + e4 * 4];
        part += qr[4*e4+0] * kv.x + qr[4*e4+1] * kv.y
              + qr[4*e4+2] * kv.z + qr[4*e4+3] * kv.w;
      }
      part += __shfl_xor(part, 1);
      part += __shfl_xor(part, 2);
      if (part > m) {                     // new max: rescale (rare)
        float f = __expf(m - part);
        m = part;
        sum *= f;
        #pragma unroll
        for (int e = 0; e < 16; ++e) acc[e] *= f;
      }
      float p = __expf(part - m);
      sum += p;
      #pragma unroll
      for (int e4 = 0; e4 < 4; ++e4) {
        float4 vv = *(const float4*)&Vs[jj][s * 16 + e4 * 4];
        acc[4*e4+0] += p * vv.x; acc[4*e4+1] += p * vv.y;
        acc[4*e4+2] += p * vv.z; acc[4*e4+3] += p * vv.w;
      }
    }
  }
  float inv = 1.f / sum;
  _Float16* od = op + (rowbase + q0 + g) * (size_t)DD + hoff + s * 16;
  #pragma unroll
  for (int e4 = 0; e4 < 4; ++e4) {
    f16x4 o4;
    o4[0] = (_Float16)(acc[4*e4+0] * inv); o4[1] = (_Float16)(acc[4*e4+1] * inv);
    o4[2] = (_Float16)(acc[4*e4+2] * inv); o4[3] = (_Float16)(acc[4*e4+3] * inv);
    *(f16x4*)(od + e4 * 4) = o4;
  }
}

extern "C" void kernel_launch(void* const* d_in, const int* in_sizes, int n_in,
                              void* d_out, int out_size, void* d_ws, size_t ws_size,
                              hipStream_t stream)
{
  const int*   x     = (const int*)d_in[0];
  const float* tok   = (const float*)d_in[1];
  const float* pos   = (const float*)d_in[2];
  const float* wq    = (const float*)d_in[3];
  const float* wk    = (const float*)d_in[4];
  const float* wv    = (const float*)d_in[5];
  const float* w_o   = (const float*)d_in[6];
  const float* b_o   = (const float*)d_in[7];
  const float* ln1_g = (const float*)d_in[8];
  const float* ln1_b = (const float*)d_in[9];
  const float* ln2_g = (const float*)d_in[10];
  const float* ln2_b = (const float*)d_in[11];
  const float* w1    = (const float*)d_in[12];
  const float* b1    = (const float*)d_in[13];
  const float* w2    = (const float*)d_in[14];
  const float* b2    = (const float*)d_in[15];
  const float* lnf_g = (const float*)d_in[16];
  const float* lnf_b = (const float*)d_in[17];
  const float* w_lm  = (const float*)d_in[18];
  const float* b_lm  = (const float*)d_in[19];
  float* out = (float*)d_out;
  char* p = (char*)d_ws;

  const size_t MB = 1024 * 1024;
  float*    h      = (float*)(p);                 // 16 MB
  float*    hn     = (float*)(p + 16 * MB);       // 16 MB
  _Float16* hn16   = (_Float16*)(p + 32 * MB);    // 8 MB
  float*    qkv    = (float*)(p + 40 * MB);       // 48 MB
  _Float16* mlp16  = (_Float16*)(p + 40 * MB);    // 32 MB (overlays qkv, dead post-attn)
  _Float16* wlm_t  = (_Float16*)(p + 72 * MB);    // 16 MB (overlays qkv tail, used after loop)
  _Float16* ob16   = (_Float16*)(p + 88 * MB);    // 8 MB
  _Float16* wqkv_t = (_Float16*)(p + 96 * MB);    // 6 MB
  _Float16* wo_t   = (_Float16*)(p + 102 * MB);   // 2 MB
  _Float16* w1_t   = (_Float16*)(p + 104 * MB);   // 8 MB
  _Float16* w2_t   = (_Float16*)(p + 112 * MB);   // 8 MB  -> total 120 MB

  embed_kernel<<<dim3(MM * DD / 4 / 256), 256, 0, stream>>>(x, tok, pos, h);

  for (int l = 0; l < LL; ++l) {
    const size_t wqo = (size_t)l * HH * DD * HSS;       // 1M
    const size_t woo = (size_t)l * HH * HSS * DD;       // 1M
    ln_kernel<<<MM, 256, 0, stream>>>(h, ln1_g + (size_t)l * DD, ln1_b + (size_t)l * DD, hn, hn16);
    prep_qkv<<<3 * 1024 * 1024 / 256, 256, 0, stream>>>(wq + wqo, wk + wqo, wv + wqo, wqkv_t);
    mfma_gemm<false,false,false,false><<<dim3(ASTR / GBN, MM / GBM), 256, 0, stream>>>(
        hn16, wqkv_t, nullptr, nullptr, qkv, MM, ASTR, DD);
    attn_kernel<<<dim3(BB * HH * (TT / QBLK)), 256, 0, stream>>>(qkv, ob16);
    tcvt<<<dim3(16, 16), 256, 0, stream>>>(w_o + woo, wo_t, DD, DD);
    mfma_gemm<false,false,true,true><<<dim3(DD / GBN, MM / GBM), 256, 0, stream>>>(
        ob16, wo_t, b_o + (size_t)l * DD, hn, h, MM, DD, DD);
    ln_kernel<<<MM, 256, 0, stream>>>(h, ln2_g + (size_t)l * DD, ln2_b + (size_t)l * DD, hn, hn16);
    tcvt<<<dim3(16, 64), 256, 0, stream>>>(w1 + (size_t)l * DD * FFD, w1_t, DD, FFD);
    mfma_gemm<true,true,true,false><<<dim3(FFD / GBN, MM / GBM), 256, 0, stream>>>(
        hn16, w1_t, b1 + (size_t)l * FFD, nullptr, mlp16, MM, FFD, DD);
    tcvt<<<dim3(64, 16), 256, 0, stream>>>(w2 + (size_t)l * FFD * DD, w2_t, FFD, DD);
    mfma_gemm<false,false,true,true><<<dim3(DD / GBN, MM / GBM), 256, 0, stream>>>(
        mlp16, w2_t, b2 + (size_t)l * DD, hn, h, MM, DD, FFD);
  }
  ln_kernel<<<MM, 256, 0, stream>>>(h, lnf_g, lnf_b, hn, hn16);
  tcvt<<<dim3(16, 128), 256, 0, stream>>>(w_lm, wlm_t, DD, VV);
  mfma_gemm<false,false,true,false><<<dim3(VV / GBN, MM / GBM), 256, 0, stream>>>(
      hn16, wlm_t, b_lm, nullptr, out, MM, VV, DD);
}

// Round 5
// 2739.641 us; speedup vs baseline: 9.8995x; 1.8403x over previous
//
#include <hip/hip_runtime.h>
#include <hip/hip_bf16.h>
#include <math.h>

#define BB 4
#define TT 1024
#define DD 1024
#define HH 16
#define HSS 64
#define LL 8
#define VV 8192
#define FFD 4096
#define MM (BB*TT)   // 4096 rows
#define ASTR 3072    // fused qkv row stride

typedef __attribute__((ext_vector_type(8))) _Float16 f16x8;
typedef __attribute__((ext_vector_type(4))) _Float16 f16x4;
typedef __attribute__((ext_vector_type(4))) float floatx4;

// async global->LDS, 16B per lane; LDS dest is wave-uniform base + lane*16
__device__ __forceinline__ void gload_lds16(const void* g, void* l) {
  __builtin_amdgcn_global_load_lds(
      (const __attribute__((address_space(1))) void*)(uintptr_t)g,
      (__attribute__((address_space(3))) void*)(uintptr_t)l, 16, 0, 0);
}

// ---------------- embedding: h = tok[x] + pos[x]  (pos indexed by TOKEN id - reference quirk)
__global__ __launch_bounds__(256) void embed_kernel(const int* __restrict__ x,
    const float* __restrict__ tok, const float* __restrict__ pos, float* __restrict__ h)
{
  int i = blockIdx.x * 256 + threadIdx.x;
  int row = i >> 8;
  int c4 = i & 255;
  int id = x[row];
  float4 a = ((const float4*)(tok + (size_t)id * DD))[c4];
  float4 b = ((const float4*)(pos + (size_t)id * DD))[c4];
  ((float4*)(h + (size_t)row * DD))[c4] = make_float4(a.x + b.x, a.y + b.y, a.z + b.z, a.w + b.w);
}

// ---------------- qkv weight prep: wq/wk/wv (H,D,HS) f32 -> fused BT [3072][1024] f16
__global__ __launch_bounds__(256) void prep_qkv(const float* __restrict__ wq,
    const float* __restrict__ wk, const float* __restrict__ wv, _Float16* __restrict__ bt)
{
  int i = blockIdx.x * 256 + threadIdx.x;   // 3*1024*1024
  int n = i >> 10, d = i & 1023;
  int m = n >> 10;
  int nn = n & 1023;
  int hh = nn >> 6, e = nn & 63;
  const float* src = (m == 0) ? wq : (m == 1) ? wk : wv;
  bt[i] = (_Float16)src[((size_t)hh * DD + d) * HSS + e];
}

// ---------------- transpose+cvt: in f32 [K][N] -> out f16 [N][K]; 64x64 LDS tiles
__global__ __launch_bounds__(256) void tcvt(const float* __restrict__ in,
    _Float16* __restrict__ out, int K, int N)
{
  __shared__ float tile[64][65];
  int bk = blockIdx.x * 64, bn = blockIdx.y * 64;
  int r = threadIdx.x >> 4, c4 = (threadIdx.x & 15) << 2;
  #pragma unroll
  for (int p = 0; p < 4; ++p) {
    float4 v = *(const float4*)(in + (size_t)(bk + p * 16 + r) * N + bn + c4);
    tile[p * 16 + r][c4 + 0] = v.x; tile[p * 16 + r][c4 + 1] = v.y;
    tile[p * 16 + r][c4 + 2] = v.z; tile[p * 16 + r][c4 + 3] = v.w;
  }
  __syncthreads();
  #pragma unroll
  for (int p = 0; p < 4; ++p) {
    int n = p * 16 + r;
    f16x4 o;
    o[0] = (_Float16)tile[c4 + 0][n]; o[1] = (_Float16)tile[c4 + 1][n];
    o[2] = (_Float16)tile[c4 + 2][n]; o[3] = (_Float16)tile[c4 + 3][n];
    *(f16x4*)(out + (size_t)(bn + n) * K + bk + c4) = o;
  }
}

// ---------------- layernorm: writes f32 (residual use) + f16 (GEMM A operand)
__global__ __launch_bounds__(256) void ln_kernel(const float* __restrict__ in,
    const float* __restrict__ g, const float* __restrict__ bta,
    float* __restrict__ out, _Float16* __restrict__ out16)
{
  __shared__ float sred[8];
  int row = blockIdx.x;
  int tid = threadIdx.x;
  float4 xv = ((const float4*)(in + (size_t)row * DD))[tid];
  float s = xv.x + xv.y + xv.z + xv.w;
  #pragma unroll
  for (int o = 32; o; o >>= 1) s += __shfl_down(s, o);
  if ((tid & 63) == 0) sred[tid >> 6] = s;
  __syncthreads();
  float mean = (sred[0] + sred[1] + sred[2] + sred[3]) * (1.f / DD);
  float d0 = xv.x - mean, d1 = xv.y - mean, d2 = xv.z - mean, d3 = xv.w - mean;
  float sq = d0 * d0 + d1 * d1 + d2 * d2 + d3 * d3;
  #pragma unroll
  for (int o = 32; o; o >>= 1) sq += __shfl_down(sq, o);
  if ((tid & 63) == 0) sred[4 + (tid >> 6)] = sq;
  __syncthreads();
  float var = (sred[4] + sred[5] + sred[6] + sred[7]) * (1.f / DD);
  float inv = rsqrtf(var + 1e-5f);
  float4 gv = ((const float4*)g)[tid];
  float4 bv = ((const float4*)bta)[tid];
  float4 ov = make_float4(d0 * inv * gv.x + bv.x, d1 * inv * gv.y + bv.y,
                          d2 * inv * gv.z + bv.z, d3 * inv * gv.w + bv.w);
  ((float4*)(out + (size_t)row * DD))[tid] = ov;
  f16x4 o16;
  o16[0] = (_Float16)ov.x; o16[1] = (_Float16)ov.y;
  o16[2] = (_Float16)ov.z; o16[3] = (_Float16)ov.w;
  *(f16x4*)(out16 + (size_t)row * DD + tid * 4) = o16;
}

// ---------------- MFMA f16 GEMM: C[M,N] = A[M,K] @ Bt[N,K]^T (+bias)(relu)(+res)
#define GBM 128
#define GBN 128
#define GBK 64
template<bool OUT16, bool RELU, bool BIAS, bool RES>
__global__ __launch_bounds__(256) void mfma_gemm(
    const _Float16* __restrict__ A, const _Float16* __restrict__ Bt,
    const float* __restrict__ bias, const float* __restrict__ res,
    void* __restrict__ Cout, int M, int N, int K)
{
  __shared__ __align__(16) _Float16 Asl[GBM * GBK];   // 16 KB, row stride 128 B
  __shared__ __align__(16) _Float16 Bsl[GBN * GBK];   // 16 KB
  const int tid = threadIdx.x;
  const int w = tid >> 6, l = tid & 63;
  const int bm = blockIdx.y * GBM, bn = blockIdx.x * GBN;
  const int wr = (w >> 1) * 64, wc = (w & 1) * 64;
  const int srow = l >> 3;            // 0..7: row within 8-row staging group
  const int scol = l & 7;             // 16B chunk within 128B row

  floatx4 acc[4][4];
  #pragma unroll
  for (int mi = 0; mi < 4; ++mi)
    #pragma unroll
    for (int ni = 0; ni < 4; ++ni) acc[mi][ni] = (floatx4){0.f, 0.f, 0.f, 0.f};

  for (int k0 = 0; k0 < K; k0 += GBK) {
    __syncthreads();
    #pragma unroll
    for (int i = 0; i < 4; ++i) {
      int rA = w * 32 + i * 8 + srow;
      const void* gpA = (const char*)(A + (size_t)(bm + rA) * K + k0) + ((scol ^ srow) << 4);
      gload_lds16(gpA, (void*)&Asl[(size_t)(w * 32 + i * 8) * GBK]);
      const void* gpB = (const char*)(Bt + (size_t)(bn + rA) * K + k0) + ((scol ^ srow) << 4);
      gload_lds16(gpB, (void*)&Bsl[(size_t)(w * 32 + i * 8) * GBK]);
    }
    __syncthreads();
    #pragma unroll
    for (int kk = 0; kk < 2; ++kk) {
      const int kbyte = kk * 64 + (l >> 4) * 16;
      f16x8 af[4], bf[4];
      #pragma unroll
      for (int mi = 0; mi < 4; ++mi) {
        int row = wr + mi * 16 + (l & 15);
        af[mi] = *(const f16x8*)((const char*)Asl + row * 128 + (kbyte ^ ((row & 7) << 4)));
      }
      #pragma unroll
      for (int ni = 0; ni < 4; ++ni) {
        int row = wc + ni * 16 + (l & 15);
        bf[ni] = *(const f16x8*)((const char*)Bsl + row * 128 + (kbyte ^ ((row & 7) << 4)));
      }
      #pragma unroll
      for (int mi = 0; mi < 4; ++mi)
        #pragma unroll
        for (int ni = 0; ni < 4; ++ni)
          acc[mi][ni] = __builtin_amdgcn_mfma_f32_16x16x32_f16(af[mi], bf[ni], acc[mi][ni], 0, 0, 0);
    }
  }

  #pragma unroll
  for (int ni = 0; ni < 4; ++ni) {
    const int col = bn + wc + ni * 16 + (l & 15);
    const float bv = BIAS ? bias[col] : 0.f;
    #pragma unroll
    for (int mi = 0; mi < 4; ++mi) {
      #pragma unroll
      for (int r = 0; r < 4; ++r) {
        const int row = bm + wr + mi * 16 + (l >> 4) * 4 + r;
        float v = acc[mi][ni][r] + bv;
        if (RELU) v = fmaxf(v, 0.f);
        if (RES) v += res[(size_t)row * N + col];
        if (OUT16) ((_Float16*)Cout)[(size_t)row * N + col] = (_Float16)v;
        else       ((float*)Cout)[(size_t)row * N + col] = v;
      }
    }
  }
}

// ---------------- MFMA causal flash attention
// Block = (b, h, 64-row q-tile), 4 waves x 16 q-rows. Q in regs (scale folded).
// K staged [kk][hs] f16 (QK^T == GEMM with Bt=K -> S[q][kk]);
// V staged transposed Vt[e][k] (PV == GEMM with Bt=Vt -> O[q][e]).
// All LDS rows XOR-swizzled: byte ^= ((row&7)<<4), both write and read sides.
// S(C/D) -> P(A-frag) layout fix via per-wave LDS round-trip (in-order, no barrier).
// qt runs DESCENDING over blockIdx to reduce the imbalance tail.
#define AQB 64
#define AKB 64
__global__ __launch_bounds__(256) void attn_mfma(const float* __restrict__ qkv,
    _Float16* __restrict__ op)
{
  __shared__ __align__(16) _Float16 Kb[AKB * HSS];     // 8 KB
  __shared__ __align__(16) _Float16 Vt[HSS * AKB];     // 8 KB, transposed
  __shared__ __align__(16) _Float16 Ps[4][16 * AKB];   // 8 KB, per-wave P
  const int qt = 15 - (blockIdx.x & 15);
  const int bh = blockIdx.x >> 4;
  const int b  = bh >> 4;
  const int hh = bh & 15;
  const int q0 = qt * AQB;
  const int t  = threadIdx.x;
  const int w  = t >> 6, l = t & 63;
  const int l16 = l & 15, g16 = l >> 4;
  const size_t rowbase = (size_t)b * TT;
  const int hoff = hh * HSS;

  // Q fragment: lane holds Q[q=w*16+l16][hs=c*32+g16*8+j], scale folded
  f16x8 aq[2];
  {
    const float* qrow = qkv + (rowbase + q0 + w * 16 + l16) * ASTR + hoff;
    #pragma unroll
    for (int c = 0; c < 2; ++c) {
      float4 v0 = *(const float4*)(qrow + c * 32 + g16 * 8);
      float4 v1 = *(const float4*)(qrow + c * 32 + g16 * 8 + 4);
      aq[c][0] = (_Float16)(v0.x * 0.125f); aq[c][1] = (_Float16)(v0.y * 0.125f);
      aq[c][2] = (_Float16)(v0.z * 0.125f); aq[c][3] = (_Float16)(v0.w * 0.125f);
      aq[c][4] = (_Float16)(v1.x * 0.125f); aq[c][5] = (_Float16)(v1.y * 0.125f);
      aq[c][6] = (_Float16)(v1.z * 0.125f); aq[c][7] = (_Float16)(v1.w * 0.125f);
    }
  }

  floatx4 oacc[4];
  #pragma unroll
  for (int ni = 0; ni < 4; ++ni) oacc[ni] = (floatx4){0.f, 0.f, 0.f, 0.f};
  float mrow[4], srow[4];
  #pragma unroll
  for (int r = 0; r < 4; ++r) { mrow[r] = -3.0e38f; srow[r] = 0.f; }

  for (int tile = 0; tile <= qt; ++tile) {
    const int j0 = tile * AKB;
    __syncthreads();                       // prev-tile readers done
    #pragma unroll
    for (int i = 0; i < 4; ++i) {          // stage K (row-swz) + V (transposed, row-swz)
      int idx = i * 256 + t;
      int rr = idx >> 4, c4 = (idx & 15) << 2;
      const float* src = qkv + (rowbase + j0 + rr) * ASTR + hoff;
      float4 kv = *(const float4*)(src + 1024 + c4);
      float4 vv = *(const float4*)(src + 2048 + c4);
      f16x4 kp;
      kp[0] = (_Float16)kv.x; kp[1] = (_Float16)kv.y;
      kp[2] = (_Float16)kv.z; kp[3] = (_Float16)kv.w;
      *(f16x4*)((char*)Kb + ((rr * 128 + c4 * 2) ^ ((rr & 7) << 4))) = kp;
      *(_Float16*)((char*)Vt + (((c4 + 0) * 128 + rr * 2) ^ (((c4 + 0) & 7) << 4))) = (_Float16)vv.x;
      *(_Float16*)((char*)Vt + (((c4 + 1) * 128 + rr * 2) ^ (((c4 + 1) & 7) << 4))) = (_Float16)vv.y;
      *(_Float16*)((char*)Vt + (((c4 + 2) * 128 + rr * 2) ^ (((c4 + 2) & 7) << 4))) = (_Float16)vv.z;
      *(_Float16*)((char*)Vt + (((c4 + 3) * 128 + rr * 2) ^ (((c4 + 3) & 7) << 4))) = (_Float16)vv.w;
    }
    __syncthreads();

    // QK^T: S[q=(g16*4+r)][kk=ni*16+l16]
    floatx4 sacc[4];
    #pragma unroll
    for (int ni = 0; ni < 4; ++ni) sacc[ni] = (floatx4){0.f, 0.f, 0.f, 0.f};
    #pragma unroll
    for (int c = 0; c < 2; ++c) {
      const int kbyte = c * 64 + g16 * 16;
      #pragma unroll
      for (int ni = 0; ni < 4; ++ni) {
        int row = ni * 16 + l16;
        f16x8 bf = *(const f16x8*)((const char*)Kb + row * 128 + (kbyte ^ ((row & 7) << 4)));
        sacc[ni] = __builtin_amdgcn_mfma_f32_16x16x32_f16(aq[c], bf, sacc[ni], 0, 0, 0);
      }
    }
    if (tile == qt) {                      // causal mask, diagonal tile only
      #pragma unroll
      for (int ni = 0; ni < 4; ++ni)
        #pragma unroll
        for (int r = 0; r < 4; ++r)
          if (ni * 16 + l16 > w * 16 + g16 * 4 + r) sacc[ni][r] = -3.0e38f;
    }
    // online softmax per row r
    #pragma unroll
    for (int r = 0; r < 4; ++r) {
      float mx = fmaxf(fmaxf(sacc[0][r], sacc[1][r]), fmaxf(sacc[2][r], sacc[3][r]));
      mx = fmaxf(mx, __shfl_xor(mx, 1));
      mx = fmaxf(mx, __shfl_xor(mx, 2));
      mx = fmaxf(mx, __shfl_xor(mx, 4));
      mx = fmaxf(mx, __shfl_xor(mx, 8));
      float mnew = fmaxf(mrow[r], mx);
      float f = __expf(mrow[r] - mnew);
      mrow[r] = mnew;
      srow[r] *= f;
      #pragma unroll
      for (int ni = 0; ni < 4; ++ni) oacc[ni][r] *= f;
    }
    #pragma unroll
    for (int ni = 0; ni < 4; ++ni)
      #pragma unroll
      for (int r = 0; r < 4; ++r)
        sacc[ni][r] = __expf(sacc[ni][r] - mrow[r]);   // P
    #pragma unroll
    for (int r = 0; r < 4; ++r) {
      float ss = sacc[0][r] + sacc[1][r] + sacc[2][r] + sacc[3][r];
      ss += __shfl_xor(ss, 1); ss += __shfl_xor(ss, 2);
      ss += __shfl_xor(ss, 4); ss += __shfl_xor(ss, 8);
      srow[r] += ss;
    }
    // P -> per-wave LDS (C/D layout -> A-frag layout)
    char* psb = (char*)&Ps[w][0];
    #pragma unroll
    for (int ni = 0; ni < 4; ++ni)
      #pragma unroll
      for (int r = 0; r < 4; ++r) {
        int q = g16 * 4 + r;
        *(_Float16*)(psb + ((q * 128 + (ni * 16 + l16) * 2) ^ ((q & 7) << 4))) = (_Float16)sacc[ni][r];
      }
    // PV: O[q][e=ni*16+l16] += P[q][k] Vt[e][k]
    #pragma unroll
    for (int c = 0; c < 2; ++c) {
      const int kbyte = c * 64 + g16 * 16;
      f16x8 ap = *(const f16x8*)(psb + l16 * 128 + (kbyte ^ ((l16 & 7) << 4)));
      #pragma unroll
      for (int ni = 0; ni < 4; ++ni) {
        int erow = ni * 16 + l16;
        f16x8 bv = *(const f16x8*)((const char*)Vt + erow * 128 + (kbyte ^ ((erow & 7) << 4)));
        oacc[ni] = __builtin_amdgcn_mfma_f32_16x16x32_f16(ap, bv, oacc[ni], 0, 0, 0);
      }
    }
  }
  // epilogue: normalize, f16 out
  #pragma unroll
  for (int r = 0; r < 4; ++r) {
    float inv = 1.f / srow[r];
    _Float16* od = op + (rowbase + q0 + w * 16 + g16 * 4 + r) * (size_t)DD + hoff;
    #pragma unroll
    for (int ni = 0; ni < 4; ++ni)
      od[ni * 16 + l16] = (_Float16)(oacc[ni][r] * inv);
  }
}

extern "C" void kernel_launch(void* const* d_in, const int* in_sizes, int n_in,
                              void* d_out, int out_size, void* d_ws, size_t ws_size,
                              hipStream_t stream)
{
  const int*   x     = (const int*)d_in[0];
  const float* tok   = (const float*)d_in[1];
  const float* pos   = (const float*)d_in[2];
  const float* wq    = (const float*)d_in[3];
  const float* wk    = (const float*)d_in[4];
  const float* wv    = (const float*)d_in[5];
  const float* w_o   = (const float*)d_in[6];
  const float* b_o   = (const float*)d_in[7];
  const float* ln1_g = (const float*)d_in[8];
  const float* ln1_b = (const float*)d_in[9];
  const float* ln2_g = (const float*)d_in[10];
  const float* ln2_b = (const float*)d_in[11];
  const float* w1    = (const float*)d_in[12];
  const float* b1    = (const float*)d_in[13];
  const float* w2    = (const float*)d_in[14];
  const float* b2    = (const float*)d_in[15];
  const float* lnf_g = (const float*)d_in[16];
  const float* lnf_b = (const float*)d_in[17];
  const float* w_lm  = (const float*)d_in[18];
  const float* b_lm  = (const float*)d_in[19];
  float* out = (float*)d_out;
  char* p = (char*)d_ws;

  const size_t MB = 1024 * 1024;
  float*    h      = (float*)(p);                 // 16 MB
  float*    hn     = (float*)(p + 16 * MB);       // 16 MB
  _Float16* hn16   = (_Float16*)(p + 32 * MB);    // 8 MB
  float*    qkv    = (float*)(p + 40 * MB);       // 48 MB
  _Float16* mlp16  = (_Float16*)(p + 40 * MB);    // 32 MB (overlays qkv, dead post-attn)
  _Float16* wlm_t  = (_Float16*)(p + 72 * MB);    // 16 MB (overlays qkv tail, used after loop)
  _Float16* ob16   = (_Float16*)(p + 88 * MB);    // 8 MB
  _Float16* wqkv_t = (_Float16*)(p + 96 * MB);    // 6 MB
  _Float16* wo_t   = (_Float16*)(p + 102 * MB);   // 2 MB
  _Float16* w1_t   = (_Float16*)(p + 104 * MB);   // 8 MB
  _Float16* w2_t   = (_Float16*)(p + 112 * MB);   // 8 MB  -> total 120 MB

  embed_kernel<<<dim3(MM * DD / 4 / 256), 256, 0, stream>>>(x, tok, pos, h);

  for (int l = 0; l < LL; ++l) {
    const size_t wqo = (size_t)l * HH * DD * HSS;       // 1M
    const size_t woo = (size_t)l * HH * HSS * DD;       // 1M
    ln_kernel<<<MM, 256, 0, stream>>>(h, ln1_g + (size_t)l * DD, ln1_b + (size_t)l * DD, hn, hn16);
    prep_qkv<<<3 * 1024 * 1024 / 256, 256, 0, stream>>>(wq + wqo, wk + wqo, wv + wqo, wqkv_t);
    mfma_gemm<false,false,false,false><<<dim3(ASTR / GBN, MM / GBM), 256, 0, stream>>>(
        hn16, wqkv_t, nullptr, nullptr, qkv, MM, ASTR, DD);
    attn_mfma<<<dim3(BB * HH * (TT / AQB)), 256, 0, stream>>>(qkv, ob16);
    tcvt<<<dim3(16, 16), 256, 0, stream>>>(w_o + woo, wo_t, DD, DD);
    mfma_gemm<false,false,true,true><<<dim3(DD / GBN, MM / GBM), 256, 0, stream>>>(
        ob16, wo_t, b_o + (size_t)l * DD, hn, h, MM, DD, DD);
    ln_kernel<<<MM, 256, 0, stream>>>(h, ln2_g + (size_t)l * DD, ln2_b + (size_t)l * DD, hn, hn16);
    tcvt<<<dim3(16, 64), 256, 0, stream>>>(w1 + (size_t)l * DD * FFD, w1_t, DD, FFD);
    mfma_gemm<true,true,true,false><<<dim3(FFD / GBN, MM / GBM), 256, 0, stream>>>(
        hn16, w1_t, b1 + (size_t)l * FFD, nullptr, mlp16, MM, FFD, DD);
    tcvt<<<dim3(64, 16), 256, 0, stream>>>(w2 + (size_t)l * FFD * DD, w2_t, FFD, DD);
    mfma_gemm<false,false,true,true><<<dim3(DD / GBN, MM / GBM), 256, 0, stream>>>(
        mlp16, w2_t, b2 + (size_t)l * DD, hn, h, MM, DD, FFD);
  }
  ln_kernel<<<MM, 256, 0, stream>>>(h, lnf_g, lnf_b, hn, hn16);
  tcvt<<<dim3(16, 128), 256, 0, stream>>>(w_lm, wlm_t, DD, VV);
  mfma_gemm<false,false,true,false><<<dim3(VV / GBN, MM / GBM), 256, 0, stream>>>(
      hn16, wlm_t, b_lm, nullptr, out, MM, VV, DD);
}

// Round 6
// 2557.771 us; speedup vs baseline: 10.6034x; 1.0711x over previous
//
#include <hip/hip_runtime.h>
#include <hip/hip_bf16.h>
#include <math.h>

#define BB 4
#define TT 1024
#define DD 1024
#define HH 16
#define HSS 64
#define LL 8
#define VV 8192
#define FFD 4096
#define MM (BB*TT)   // 4096 rows
#define ASTR 3072    // fused qkv row stride (f16)

typedef __attribute__((ext_vector_type(8))) _Float16 f16x8;
typedef __attribute__((ext_vector_type(4))) _Float16 f16x4;
typedef __attribute__((ext_vector_type(4))) float floatx4;

// async global->LDS, 16B per lane; LDS dest is wave-uniform base + lane*16
__device__ __forceinline__ void gload_lds16(const void* g, void* l) {
  __builtin_amdgcn_global_load_lds(
      (const __attribute__((address_space(1))) void*)(uintptr_t)g,
      (__attribute__((address_space(3))) void*)(uintptr_t)l, 16, 0, 0);
}

// ---------------- embedding: h = tok[x] + pos[x]  (pos indexed by TOKEN id - reference quirk)
__global__ __launch_bounds__(256) void embed_kernel(const int* __restrict__ x,
    const float* __restrict__ tok, const float* __restrict__ pos, float* __restrict__ h)
{
  int i = blockIdx.x * 256 + threadIdx.x;
  int row = i >> 8;
  int c4 = i & 255;
  int id = x[row];
  float4 a = ((const float4*)(tok + (size_t)id * DD))[c4];
  float4 b = ((const float4*)(pos + (size_t)id * DD))[c4];
  ((float4*)(h + (size_t)row * DD))[c4] = make_float4(a.x + b.x, a.y + b.y, a.z + b.z, a.w + b.w);
}

// ---------------- qkv weight prep: wq/wk/wv (H,D,HS) f32 -> fused BT [3072][1024] f16
// attention scale 1/8 folded into the q-part weights.
__global__ __launch_bounds__(256) void prep_qkv(const float* __restrict__ wq,
    const float* __restrict__ wk, const float* __restrict__ wv, _Float16* __restrict__ bt)
{
  int i = blockIdx.x * 256 + threadIdx.x;   // 3*1024*1024
  int n = i >> 10, d = i & 1023;
  int m = n >> 10;
  int nn = n & 1023;
  int hh = nn >> 6, e = nn & 63;
  const float* src = (m == 0) ? wq : (m == 1) ? wk : wv;
  float v = src[((size_t)hh * DD + d) * HSS + e];
  if (m == 0) v *= 0.125f;
  bt[i] = (_Float16)v;
}

// ---------------- transpose+cvt: in f32 [K][N] -> out f16 [N][K]; 64x64 LDS tiles
__global__ __launch_bounds__(256) void tcvt(const float* __restrict__ in,
    _Float16* __restrict__ out, int K, int N)
{
  __shared__ float tile[64][65];
  int bk = blockIdx.x * 64, bn = blockIdx.y * 64;
  int r = threadIdx.x >> 4, c4 = (threadIdx.x & 15) << 2;
  #pragma unroll
  for (int p = 0; p < 4; ++p) {
    float4 v = *(const float4*)(in + (size_t)(bk + p * 16 + r) * N + bn + c4);
    tile[p * 16 + r][c4 + 0] = v.x; tile[p * 16 + r][c4 + 1] = v.y;
    tile[p * 16 + r][c4 + 2] = v.z; tile[p * 16 + r][c4 + 3] = v.w;
  }
  __syncthreads();
  #pragma unroll
  for (int p = 0; p < 4; ++p) {
    int n = p * 16 + r;
    f16x4 o;
    o[0] = (_Float16)tile[c4 + 0][n]; o[1] = (_Float16)tile[c4 + 1][n];
    o[2] = (_Float16)tile[c4 + 2][n]; o[3] = (_Float16)tile[c4 + 3][n];
    *(f16x4*)(out + (size_t)(bn + n) * K + bk + c4) = o;
  }
}

// ---------------- v transpose: qkv16 v-part [b*T+t][2048+h*64+e] -> vt[(b*16+h)*64+e][t]
__global__ __launch_bounds__(256) void vtr_kernel(const _Float16* __restrict__ qkv16,
    _Float16* __restrict__ vt)
{
  __shared__ _Float16 tile[64][80];   // pad 80: 16B-aligned rows, conflict-light
  const int bh = blockIdx.x >> 4;     // 0..63
  const int tt = blockIdx.x & 15;
  const int b = bh >> 4, hh = bh & 15;
  const int t0 = tt * 64;
  const int tid = threadIdx.x;
  #pragma unroll
  for (int i = 0; i < 2; ++i) {
    int idx = i * 256 + tid;
    int rowt = idx >> 3, ch = idx & 7;
    f16x8 v = *(const f16x8*)(qkv16 + ((size_t)b * TT + t0 + rowt) * ASTR + 2048 + hh * 64 + ch * 8);
    *(f16x8*)&tile[rowt][ch * 8] = v;
  }
  __syncthreads();
  #pragma unroll
  for (int i = 0; i < 2; ++i) {
    int idx = i * 256 + tid;
    int e = idx & 63, c = idx >> 6;   // c 0..7
    f16x8 o;
    #pragma unroll
    for (int j = 0; j < 8; ++j) o[j] = tile[c * 8 + j][e];
    *(f16x8*)(vt + ((size_t)bh * 64 + e) * TT + t0 + c * 8) = o;
  }
}

// ---------------- layernorm: writes f32 (residual use) + f16 (GEMM A operand)
__global__ __launch_bounds__(256) void ln_kernel(const float* __restrict__ in,
    const float* __restrict__ g, const float* __restrict__ bta,
    float* __restrict__ out, _Float16* __restrict__ out16)
{
  __shared__ float sred[8];
  int row = blockIdx.x;
  int tid = threadIdx.x;
  float4 xv = ((const float4*)(in + (size_t)row * DD))[tid];
  float s = xv.x + xv.y + xv.z + xv.w;
  #pragma unroll
  for (int o = 32; o; o >>= 1) s += __shfl_down(s, o);
  if ((tid & 63) == 0) sred[tid >> 6] = s;
  __syncthreads();
  float mean = (sred[0] + sred[1] + sred[2] + sred[3]) * (1.f / DD);
  float d0 = xv.x - mean, d1 = xv.y - mean, d2 = xv.z - mean, d3 = xv.w - mean;
  float sq = d0 * d0 + d1 * d1 + d2 * d2 + d3 * d3;
  #pragma unroll
  for (int o = 32; o; o >>= 1) sq += __shfl_down(sq, o);
  if ((tid & 63) == 0) sred[4 + (tid >> 6)] = sq;
  __syncthreads();
  float var = (sred[4] + sred[5] + sred[6] + sred[7]) * (1.f / DD);
  float inv = rsqrtf(var + 1e-5f);
  float4 gv = ((const float4*)g)[tid];
  float4 bv = ((const float4*)bta)[tid];
  float4 ov = make_float4(d0 * inv * gv.x + bv.x, d1 * inv * gv.y + bv.y,
                          d2 * inv * gv.z + bv.z, d3 * inv * gv.w + bv.w);
  ((float4*)(out + (size_t)row * DD))[tid] = ov;
  f16x4 o16;
  o16[0] = (_Float16)ov.x; o16[1] = (_Float16)ov.y;
  o16[2] = (_Float16)ov.z; o16[3] = (_Float16)ov.w;
  *(f16x4*)(out16 + (size_t)row * DD + tid * 4) = o16;
}

// ---------------- MFMA f16 GEMM: C[M,N] = A[M,K] @ Bt[N,K]^T (+bias)(relu)(+res)
#define GBM 128
#define GBN 128
#define GBK 64
template<bool OUT16, bool RELU, bool BIAS, bool RES>
__global__ __launch_bounds__(256) void mfma_gemm(
    const _Float16* __restrict__ A, const _Float16* __restrict__ Bt,
    const float* __restrict__ bias, const float* __restrict__ res,
    void* __restrict__ Cout, int M, int N, int K)
{
  __shared__ __align__(16) _Float16 Asl[GBM * GBK];   // 16 KB, row stride 128 B
  __shared__ __align__(16) _Float16 Bsl[GBN * GBK];   // 16 KB
  const int tid = threadIdx.x;
  const int w = tid >> 6, l = tid & 63;
  const int bm = blockIdx.y * GBM, bn = blockIdx.x * GBN;
  const int wr = (w >> 1) * 64, wc = (w & 1) * 64;
  const int srow = l >> 3;
  const int scol = l & 7;

  floatx4 acc[4][4];
  #pragma unroll
  for (int mi = 0; mi < 4; ++mi)
    #pragma unroll
    for (int ni = 0; ni < 4; ++ni) acc[mi][ni] = (floatx4){0.f, 0.f, 0.f, 0.f};

  for (int k0 = 0; k0 < K; k0 += GBK) {
    __syncthreads();
    #pragma unroll
    for (int i = 0; i < 4; ++i) {
      int rA = w * 32 + i * 8 + srow;
      const void* gpA = (const char*)(A + (size_t)(bm + rA) * K + k0) + ((scol ^ srow) << 4);
      gload_lds16(gpA, (void*)&Asl[(size_t)(w * 32 + i * 8) * GBK]);
      const void* gpB = (const char*)(Bt + (size_t)(bn + rA) * K + k0) + ((scol ^ srow) << 4);
      gload_lds16(gpB, (void*)&Bsl[(size_t)(w * 32 + i * 8) * GBK]);
    }
    __syncthreads();
    #pragma unroll
    for (int kk = 0; kk < 2; ++kk) {
      const int kbyte = kk * 64 + (l >> 4) * 16;
      f16x8 af[4], bf[4];
      #pragma unroll
      for (int mi = 0; mi < 4; ++mi) {
        int row = wr + mi * 16 + (l & 15);
        af[mi] = *(const f16x8*)((const char*)Asl + row * 128 + (kbyte ^ ((row & 7) << 4)));
      }
      #pragma unroll
      for (int ni = 0; ni < 4; ++ni) {
        int row = wc + ni * 16 + (l & 15);
        bf[ni] = *(const f16x8*)((const char*)Bsl + row * 128 + (kbyte ^ ((row & 7) << 4)));
      }
      #pragma unroll
      for (int mi = 0; mi < 4; ++mi)
        #pragma unroll
        for (int ni = 0; ni < 4; ++ni)
          acc[mi][ni] = __builtin_amdgcn_mfma_f32_16x16x32_f16(af[mi], bf[ni], acc[mi][ni], 0, 0, 0);
    }
  }

  #pragma unroll
  for (int ni = 0; ni < 4; ++ni) {
    const int col = bn + wc + ni * 16 + (l & 15);
    const float bv = BIAS ? bias[col] : 0.f;
    #pragma unroll
    for (int mi = 0; mi < 4; ++mi) {
      #pragma unroll
      for (int r = 0; r < 4; ++r) {
        const int row = bm + wr + mi * 16 + (l >> 4) * 4 + r;
        float v = acc[mi][ni][r] + bv;
        if (RELU) v = fmaxf(v, 0.f);
        if (RES) v += res[(size_t)row * N + col];
        if (OUT16) ((_Float16*)Cout)[(size_t)row * N + col] = (_Float16)v;
        else       ((float*)Cout)[(size_t)row * N + col] = v;
      }
    }
  }
}

// ---------------- MFMA causal flash attention (f16 qkv + pre-transposed V)
// Block = (b, h, 64-row q-tile), 4 waves x 16 q-rows. Q in regs (scale pre-folded).
// K, Vt staged via global_load_lds w16 with pre-swizzled global source
// (LDS linear [row][128B], read at byte ^ ((row&7)<<4)) - proven mfma_gemm pattern.
// S(C/D)->P(A-frag) via per-wave LDS round-trip. qt DESCENDING for tail balance.
#define AQB 64
#define AKB 64
__global__ __launch_bounds__(256) void attn_mfma(const _Float16* __restrict__ qkv16,
    const _Float16* __restrict__ vt16, _Float16* __restrict__ op)
{
  __shared__ __align__(16) _Float16 Kb[AKB * HSS];     // 8 KB
  __shared__ __align__(16) _Float16 Vtb[HSS * AKB];    // 8 KB
  __shared__ __align__(16) _Float16 Ps[4][16 * AKB];   // 8 KB, per-wave P
  const int qt = 15 - (blockIdx.x & 15);
  const int bh = blockIdx.x >> 4;
  const int b  = bh >> 4;
  const int hh = bh & 15;
  const int q0 = qt * AQB;
  const int t  = threadIdx.x;
  const int w  = t >> 6, l = t & 63;
  const int l16 = l & 15, g16 = l >> 4;
  const size_t rowbase = (size_t)b * TT;
  const int hoff = hh * HSS;
  const size_t vbase = (size_t)bh * 64;    // vt16 row block for this (b,h)
  const int rgrp = l >> 3, chunk = l & 7;  // staging decomposition

  // Q fragment: lane holds Q[q=w*16+l16][hs=c*32+g16*8 .. +8]  (scale in weights)
  f16x8 aq[2];
  {
    const _Float16* qrow = qkv16 + (rowbase + q0 + w * 16 + l16) * ASTR + hoff;
    aq[0] = *(const f16x8*)(qrow + g16 * 8);
    aq[1] = *(const f16x8*)(qrow + 32 + g16 * 8);
  }

  floatx4 oacc[4];
  #pragma unroll
  for (int ni = 0; ni < 4; ++ni) oacc[ni] = (floatx4){0.f, 0.f, 0.f, 0.f};
  float mrow[4], srow[4];
  #pragma unroll
  for (int r = 0; r < 4; ++r) { mrow[r] = -3.0e38f; srow[r] = 0.f; }

  for (int tile = 0; tile <= qt; ++tile) {
    const int j0 = tile * AKB;
    __syncthreads();                       // prev-tile readers done
    #pragma unroll
    for (int i = 0; i < 2; ++i) {          // stage K rows + Vt rows (8 rows/wave/issue)
      const int rk = w * 16 + i * 8 + rgrp;
      const char* gK = (const char*)(qkv16 + (rowbase + j0 + rk) * ASTR + 1024 + hoff)
                     + ((chunk ^ (rk & 7)) << 4);
      gload_lds16(gK, (void*)((char*)Kb + (w * 16 + i * 8) * 128));
      const char* gV = (const char*)(vt16 + (vbase + rk) * TT + j0)
                     + ((chunk ^ (rk & 7)) << 4);
      gload_lds16(gV, (void*)((char*)Vtb + (w * 16 + i * 8) * 128));
    }
    __syncthreads();

    // QK^T: S[q=(g16*4+r)][kk=ni*16+l16]
    floatx4 sacc[4];
    #pragma unroll
    for (int ni = 0; ni < 4; ++ni) sacc[ni] = (floatx4){0.f, 0.f, 0.f, 0.f};
    #pragma unroll
    for (int c = 0; c < 2; ++c) {
      const int kbyte = c * 64 + g16 * 16;
      #pragma unroll
      for (int ni = 0; ni < 4; ++ni) {
        int row = ni * 16 + l16;
        f16x8 bf = *(const f16x8*)((const char*)Kb + row * 128 + (kbyte ^ ((row & 7) << 4)));
        sacc[ni] = __builtin_amdgcn_mfma_f32_16x16x32_f16(aq[c], bf, sacc[ni], 0, 0, 0);
      }
    }
    if (tile == qt) {                      // causal mask, diagonal tile only
      #pragma unroll
      for (int ni = 0; ni < 4; ++ni)
        #pragma unroll
        for (int r = 0; r < 4; ++r)
          if (ni * 16 + l16 > w * 16 + g16 * 4 + r) sacc[ni][r] = -3.0e38f;
    }
    // online softmax per row r
    #pragma unroll
    for (int r = 0; r < 4; ++r) {
      float mx = fmaxf(fmaxf(sacc[0][r], sacc[1][r]), fmaxf(sacc[2][r], sacc[3][r]));
      mx = fmaxf(mx, __shfl_xor(mx, 1));
      mx = fmaxf(mx, __shfl_xor(mx, 2));
      mx = fmaxf(mx, __shfl_xor(mx, 4));
      mx = fmaxf(mx, __shfl_xor(mx, 8));
      float mnew = fmaxf(mrow[r], mx);
      float f = __expf(mrow[r] - mnew);
      mrow[r] = mnew;
      srow[r] *= f;
      #pragma unroll
      for (int ni = 0; ni < 4; ++ni) oacc[ni][r] *= f;
    }
    #pragma unroll
    for (int ni = 0; ni < 4; ++ni)
      #pragma unroll
      for (int r = 0; r < 4; ++r)
        sacc[ni][r] = __expf(sacc[ni][r] - mrow[r]);   // P
    #pragma unroll
    for (int r = 0; r < 4; ++r) {
      float ss = sacc[0][r] + sacc[1][r] + sacc[2][r] + sacc[3][r];
      ss += __shfl_xor(ss, 1); ss += __shfl_xor(ss, 2);
      ss += __shfl_xor(ss, 4); ss += __shfl_xor(ss, 8);
      srow[r] += ss;
    }
    // P -> per-wave LDS (C/D layout -> A-frag layout)
    char* psb = (char*)&Ps[w][0];
    #pragma unroll
    for (int ni = 0; ni < 4; ++ni)
      #pragma unroll
      for (int r = 0; r < 4; ++r) {
        int q = g16 * 4 + r;
        *(_Float16*)(psb + ((q * 128 + (ni * 16 + l16) * 2) ^ ((q & 7) << 4))) = (_Float16)sacc[ni][r];
      }
    // PV: O[q][e=ni*16+l16] += P[q][k] Vt[e][k]
    #pragma unroll
    for (int c = 0; c < 2; ++c) {
      const int kbyte = c * 64 + g16 * 16;
      f16x8 ap = *(const f16x8*)(psb + l16 * 128 + (kbyte ^ ((l16 & 7) << 4)));
      #pragma unroll
      for (int ni = 0; ni < 4; ++ni) {
        int erow = ni * 16 + l16;
        f16x8 bv = *(const f16x8*)((const char*)Vtb + erow * 128 + (kbyte ^ ((erow & 7) << 4)));
        oacc[ni] = __builtin_amdgcn_mfma_f32_16x16x32_f16(ap, bv, oacc[ni], 0, 0, 0);
      }
    }
  }
  // epilogue: normalize, f16 out
  #pragma unroll
  for (int r = 0; r < 4; ++r) {
    float inv = 1.f / srow[r];
    _Float16* od = op + (rowbase + q0 + w * 16 + g16 * 4 + r) * (size_t)DD + hoff;
    #pragma unroll
    for (int ni = 0; ni < 4; ++ni)
      od[ni * 16 + l16] = (_Float16)(oacc[ni][r] * inv);
  }
}

extern "C" void kernel_launch(void* const* d_in, const int* in_sizes, int n_in,
                              void* d_out, int out_size, void* d_ws, size_t ws_size,
                              hipStream_t stream)
{
  const int*   x     = (const int*)d_in[0];
  const float* tok   = (const float*)d_in[1];
  const float* pos   = (const float*)d_in[2];
  const float* wq    = (const float*)d_in[3];
  const float* wk    = (const float*)d_in[4];
  const float* wv    = (const float*)d_in[5];
  const float* w_o   = (const float*)d_in[6];
  const float* b_o   = (const float*)d_in[7];
  const float* ln1_g = (const float*)d_in[8];
  const float* ln1_b = (const float*)d_in[9];
  const float* ln2_g = (const float*)d_in[10];
  const float* ln2_b = (const float*)d_in[11];
  const float* w1    = (const float*)d_in[12];
  const float* b1    = (const float*)d_in[13];
  const float* w2    = (const float*)d_in[14];
  const float* b2    = (const float*)d_in[15];
  const float* lnf_g = (const float*)d_in[16];
  const float* lnf_b = (const float*)d_in[17];
  const float* w_lm  = (const float*)d_in[18];
  const float* b_lm  = (const float*)d_in[19];
  float* out = (float*)d_out;
  char* p = (char*)d_ws;

  const size_t MB = 1024 * 1024;
  float*    h      = (float*)(p);                 // 16 MB
  float*    hn     = (float*)(p + 16 * MB);       // 16 MB
  _Float16* hn16   = (_Float16*)(p + 32 * MB);    // 8 MB
  _Float16* qkv16  = (_Float16*)(p + 40 * MB);    // 24 MB (per-layer)
  _Float16* vt16   = (_Float16*)(p + 64 * MB);    // 8 MB  (per-layer)
  _Float16* mlp16  = (_Float16*)(p + 40 * MB);    // 32 MB, overlays qkv16+vt16 (dead post-attn)
  _Float16* wlm_t  = (_Float16*)(p + 40 * MB);    // 16 MB, overlays (used after loop)
  _Float16* ob16   = (_Float16*)(p + 72 * MB);    // 8 MB
  _Float16* wqkv_t = (_Float16*)(p + 80 * MB);    // 6 MB
  _Float16* wo_t   = (_Float16*)(p + 86 * MB);    // 2 MB
  _Float16* w1_t   = (_Float16*)(p + 88 * MB);    // 8 MB
  _Float16* w2_t   = (_Float16*)(p + 96 * MB);    // 8 MB  -> total 104 MB

  embed_kernel<<<dim3(MM * DD / 4 / 256), 256, 0, stream>>>(x, tok, pos, h);

  for (int l = 0; l < LL; ++l) {
    const size_t wqo = (size_t)l * HH * DD * HSS;
    const size_t woo = (size_t)l * HH * HSS * DD;
    ln_kernel<<<MM, 256, 0, stream>>>(h, ln1_g + (size_t)l * DD, ln1_b + (size_t)l * DD, hn, hn16);
    prep_qkv<<<3 * 1024 * 1024 / 256, 256, 0, stream>>>(wq + wqo, wk + wqo, wv + wqo, wqkv_t);
    mfma_gemm<true,false,false,false><<<dim3(ASTR / GBN, MM / GBM), 256, 0, stream>>>(
        hn16, wqkv_t, nullptr, nullptr, qkv16, MM, ASTR, DD);
    vtr_kernel<<<dim3(BB * HH * (TT / 64)), 256, 0, stream>>>(qkv16, vt16);
    attn_mfma<<<dim3(BB * HH * (TT / AQB)), 256, 0, stream>>>(qkv16, vt16, ob16);
    tcvt<<<dim3(16, 16), 256, 0, stream>>>(w_o + woo, wo_t, DD, DD);
    mfma_gemm<false,false,true,true><<<dim3(DD / GBN, MM / GBM), 256, 0, stream>>>(
        ob16, wo_t, b_o + (size_t)l * DD, hn, h, MM, DD, DD);
    ln_kernel<<<MM, 256, 0, stream>>>(h, ln2_g + (size_t)l * DD, ln2_b + (size_t)l * DD, hn, hn16);
    tcvt<<<dim3(16, 64), 256, 0, stream>>>(w1 + (size_t)l * DD * FFD, w1_t, DD, FFD);
    mfma_gemm<true,true,true,false><<<dim3(FFD / GBN, MM / GBM), 256, 0, stream>>>(
        hn16, w1_t, b1 + (size_t)l * FFD, nullptr, mlp16, MM, FFD, DD);
    tcvt<<<dim3(64, 16), 256, 0, stream>>>(w2 + (size_t)l * FFD * DD, w2_t, FFD, DD);
    mfma_gemm<false,false,true,true><<<dim3(DD / GBN, MM / GBM), 256, 0, stream>>>(
        mlp16, w2_t, b2 + (size_t)l * DD, hn, h, MM, DD, FFD);
  }
  ln_kernel<<<MM, 256, 0, stream>>>(h, lnf_g, lnf_b, hn, hn16);
  tcvt<<<dim3(16, 128), 256, 0, stream>>>(w_lm, wlm_t, DD, VV);
  mfma_gemm<false,false,true,false><<<dim3(VV / GBN, MM / GBM), 256, 0, stream>>>(
      hn16, wlm_t, b_lm, nullptr, out, MM, VV, DD);
}